// Round 1
// baseline (281.033 us; speedup 1.0000x reference)
//
#include <hip/hip_runtime.h>
#include <cstdint>
#include <cstddef>

// ---------------- types ----------------
typedef _Float16 h8 __attribute__((ext_vector_type(8)));
typedef _Float16 h4 __attribute__((ext_vector_type(4)));
typedef float    f32x4 __attribute__((ext_vector_type(4)));

constexpr int B_ = 8, N_ = 1024, E_ = 512, H_ = 8, D_ = 64, F_ = 2048;
constexpr int M_ = B_ * N_;   // 8192 rows
constexpr int HD_ = H_ * D_;  // 512

#define GLOAD_LDS16(gp, lp)                                                        \
    __builtin_amdgcn_global_load_lds((const __attribute__((address_space(1))) void*)(gp), \
                                     (__attribute__((address_space(3))) void*)(lp), 16, 0, 0)

// ---------------- f32 -> f16 elementwise ----------------
__global__ void __launch_bounds__(256) k_cvt(const float* __restrict__ in,
                                             _Float16* __restrict__ out, int n) {
    int i = (blockIdx.x * 256 + threadIdx.x) * 4;
    if (i + 3 < n) {
        float4 v = *(const float4*)(in + i);
        h4 o = {(_Float16)v.x, (_Float16)v.y, (_Float16)v.z, (_Float16)v.w};
        *(h4*)(out + i) = o;
    }
}

// ---------------- transpose f32 [R][C] -> f16 [C][R] ----------------
__global__ void __launch_bounds__(256) k_tr(const float* __restrict__ in,
                                            _Float16* __restrict__ out, int R, int C) {
    int t = blockIdx.x * 256 + threadIdx.x;
    if (t < R * C) {
        int c = t / R, r = t - c * R;
        out[t] = (_Float16)in[r * C + c];  // out[c][r] = in[r][c]
    }
}

// ---------------- GEMM: C = A[M][K] * Bt[N][K]^T, f16 in, fp32 acc ----------------
// EPI 0: scatter to q/k/vT f16 buffers (QKV projection, N=1536)
// EPI 1: outf = acc + bias[col] + res[row][col]  (fp32)
// EPI 2: outh = relu(acc + bias[col])            (f16)
template <int EPI>
__global__ void __launch_bounds__(256) k_gemm(
    const _Float16* __restrict__ A, const _Float16* __restrict__ Bt,
    int Mg, int Ng, int Kg,
    const float* __restrict__ bias, const float* __restrict__ res,
    float* __restrict__ outf, _Float16* __restrict__ outh,
    _Float16* __restrict__ qp, _Float16* __restrict__ kp, _Float16* __restrict__ vtp) {
    __shared__ alignas(16) _Float16 lA[128 * 64];
    __shared__ alignas(16) _Float16 lB[128 * 64];

    const int tid = threadIdx.x;
    const int lane = tid & 63;
    const int wid = tid >> 6;
    const int wr = wid >> 1, wc = wid & 1;      // 2x2 wave grid, each 64x64
    const int m0 = blockIdx.y * 128, n0 = blockIdx.x * 128;
    const int lrow = tid >> 3;                  // 0..31 rows per staging issue
    const int lcol = (tid & 7) * 8;             // 8 f16 per thread
    const int r16 = lane & 15, hseg = lane >> 4;

    f32x4 acc[4][4] = {};

    for (int k0 = 0; k0 < Kg; k0 += 64) {
        __syncthreads();
#pragma unroll
        for (int i = 0; i < 4; ++i) {
            const _Float16* gp = A + (size_t)(m0 + i * 32 + lrow) * Kg + k0 + lcol;
            GLOAD_LDS16(gp, lA + (i * 256 + tid) * 8);
        }
#pragma unroll
        for (int i = 0; i < 4; ++i) {
            const _Float16* gp = Bt + (size_t)(n0 + i * 32 + lrow) * Kg + k0 + lcol;
            GLOAD_LDS16(gp, lB + (i * 256 + tid) * 8);
        }
        __syncthreads();  // compiler drains vmcnt before barrier

#pragma unroll
        for (int kk = 0; kk < 2; ++kk) {
            h8 af[4], bf[4];
#pragma unroll
            for (int mi = 0; mi < 4; ++mi)
                af[mi] = *(const h8*)&lA[(wr * 64 + mi * 16 + r16) * 64 + kk * 32 + hseg * 8];
#pragma unroll
            for (int ni = 0; ni < 4; ++ni)
                bf[ni] = *(const h8*)&lB[(wc * 64 + ni * 16 + r16) * 64 + kk * 32 + hseg * 8];
#pragma unroll
            for (int mi = 0; mi < 4; ++mi)
#pragma unroll
                for (int ni = 0; ni < 4; ++ni)
                    acc[mi][ni] =
                        __builtin_amdgcn_mfma_f32_16x16x32_f16(af[mi], bf[ni], acc[mi][ni], 0, 0, 0);
        }
    }

    // epilogue: lane holds C[row = m0+wr*64+mi*16+hseg*4+r][col = n0+wc*64+ni*16+r16]
#pragma unroll
    for (int mi = 0; mi < 4; ++mi) {
#pragma unroll
        for (int ni = 0; ni < 4; ++ni) {
#pragma unroll
            for (int r = 0; r < 4; ++r) {
                int row = m0 + wr * 64 + mi * 16 + hseg * 4 + r;
                int col = n0 + wc * 64 + ni * 16 + r16;
                float v = acc[mi][ni][r];
                if constexpr (EPI == 0) {
                    int seg = col >> 9, cc = col & 511;
                    int h = cc >> 6, d = cc & 63;
                    int b = row >> 10, nn = row & 1023;
                    if (seg == 0)
                        qp[((b * 8 + h) * 1024 + nn) * 64 + d] = (_Float16)v;
                    else if (seg == 1)
                        kp[((b * 8 + h) * 1024 + nn) * 64 + d] = (_Float16)v;
                    else
                        vtp[((b * 8 + h) * 64 + d) * 1024 + nn] = (_Float16)v;
                } else if constexpr (EPI == 1) {
                    outf[(size_t)row * Ng + col] = v + bias[col] + res[(size_t)row * Ng + col];
                } else {
                    float t = v + bias[col];
                    outh[(size_t)row * Ng + col] = (_Float16)(t > 0.f ? t : 0.f);
                }
            }
        }
    }
}

// ---------------- flash attention: 1 block = (b,h) x 64 q-rows ----------------
__global__ void __launch_bounds__(256) k_attn(const _Float16* __restrict__ q,
                                              const _Float16* __restrict__ k,
                                              const _Float16* __restrict__ vt,
                                              _Float16* __restrict__ attn) {
    __shared__ alignas(16) _Float16 lK[64 * 64];      // [key][d]
    __shared__ alignas(16) _Float16 lV[64 * 64];      // [d][key]
    __shared__ alignas(16) _Float16 lP[4 * 16 * 64];  // per-wave P tile

    const int tid = threadIdx.x, lane = tid & 63, w = tid >> 6;
    const int bh = blockIdx.y;
    const int q0 = blockIdx.x * 64;
    const int r16 = lane & 15, hseg = lane >> 4;
    const size_t base = (size_t)bh * N_ * D_;

    // Q fragments for this wave's 16 q-rows, held for the whole kernel
    h8 qf[2];
#pragma unroll
    for (int kc = 0; kc < 2; ++kc)
        qf[kc] = *(const h8*)&q[base + (size_t)(q0 + w * 16 + r16) * 64 + kc * 32 + hseg * 8];

    float mrun[4], lrun[4];
    f32x4 oacc[4] = {};
#pragma unroll
    for (int r = 0; r < 4; ++r) { mrun[r] = -1e30f; lrun[r] = 0.f; }

    for (int kt = 0; kt < N_ / 64; ++kt) {
        __syncthreads();
#pragma unroll
        for (int i = 0; i < 2; ++i) {  // K tile: contiguous [64][64]
            const _Float16* gp = k + base + kt * 4096 + (i * 256 + tid) * 8;
            GLOAD_LDS16(gp, lK + (i * 256 + tid) * 8);
        }
#pragma unroll
        for (int i = 0; i < 2; ++i) {  // Vt tile: 64 rows of [D][N]
            int rr = i * 32 + (tid >> 3);
            const _Float16* gp = vt + base + (size_t)rr * N_ + kt * 64 + (tid & 7) * 8;
            GLOAD_LDS16(gp, lV + (i * 256 + tid) * 8);
        }
        __syncthreads();

        // S tiles: 4 x (16q x 16key), K-dim = D = 64
        float sv[4][4];
#pragma unroll
        for (int t4 = 0; t4 < 4; ++t4) {
            f32x4 a = {};
#pragma unroll
            for (int kc = 0; kc < 2; ++kc) {
                h8 kf = *(const h8*)&lK[(t4 * 16 + r16) * 64 + kc * 32 + hseg * 8];
                a = __builtin_amdgcn_mfma_f32_16x16x32_f16(qf[kc], kf, a, 0, 0, 0);
            }
#pragma unroll
            for (int r = 0; r < 4; ++r) sv[t4][r] = a[r] * 0.125f;  // 1/sqrt(64)
        }

        // online softmax update (rows = hseg*4+r; reduce across the 16 cols/lanes)
        float p[4][4];
#pragma unroll
        for (int r = 0; r < 4; ++r) {
            float mx = fmaxf(fmaxf(sv[0][r], sv[1][r]), fmaxf(sv[2][r], sv[3][r]));
#pragma unroll
            for (int msk = 1; msk < 16; msk <<= 1) mx = fmaxf(mx, __shfl_xor(mx, msk));
            float mnew = fmaxf(mrun[r], mx);
            float sc = expf(mrun[r] - mnew);
            float rsum = 0.f;
#pragma unroll
            for (int t4 = 0; t4 < 4; ++t4) {
                float pv = expf(sv[t4][r] - mnew);
                p[t4][r] = pv;
                rsum += pv;
            }
#pragma unroll
            for (int msk = 1; msk < 16; msk <<= 1) rsum += __shfl_xor(rsum, msk);
            lrun[r] = lrun[r] * sc + rsum;
            mrun[r] = mnew;
#pragma unroll
            for (int nf = 0; nf < 4; ++nf) oacc[nf][r] *= sc;
        }

        // redistribute P (D-layout) -> A-operand layout via per-wave LDS
#pragma unroll
        for (int t4 = 0; t4 < 4; ++t4)
#pragma unroll
            for (int r = 0; r < 4; ++r)
                lP[w * 1024 + (hseg * 4 + r) * 64 + t4 * 16 + r16] = (_Float16)p[t4][r];
        asm volatile("s_waitcnt lgkmcnt(0)" ::: "memory");  // wave-internal LDS fence

        h8 pa[2];
#pragma unroll
        for (int kc = 0; kc < 2; ++kc)
            pa[kc] = *(const h8*)&lP[w * 1024 + r16 * 64 + kc * 32 + hseg * 8];
#pragma unroll
        for (int nf = 0; nf < 4; ++nf)
#pragma unroll
            for (int kc = 0; kc < 2; ++kc) {
                h8 vb = *(const h8*)&lV[(nf * 16 + r16) * 64 + kc * 32 + hseg * 8];
                oacc[nf] = __builtin_amdgcn_mfma_f32_16x16x32_f16(pa[kc], vb, oacc[nf], 0, 0, 0);
            }
    }

    // write attn_out [M][HD] f16
    int b = bh >> 3, h = bh & 7;
#pragma unroll
    for (int nf = 0; nf < 4; ++nf)
#pragma unroll
        for (int r = 0; r < 4; ++r) {
            int row = b * 1024 + q0 + w * 16 + hseg * 4 + r;
            int col = h * 64 + nf * 16 + r16;
            attn[(size_t)row * 512 + col] = (_Float16)(oacc[nf][r] / lrun[r]);
        }
}

// ---------------- layernorm: 1 wave per row of 512 ----------------
__global__ void __launch_bounds__(256) k_ln(const float* __restrict__ x,
                                            const float* __restrict__ g,
                                            const float* __restrict__ b,
                                            float* __restrict__ outf,
                                            _Float16* __restrict__ outh) {
    int row = blockIdx.x * 4 + (threadIdx.x >> 6);
    int lane = threadIdx.x & 63;
    const float* xr = x + (size_t)row * 512;
    float4 v0 = *(const float4*)(xr + lane * 8);
    float4 v1 = *(const float4*)(xr + lane * 8 + 4);
    float s = v0.x + v0.y + v0.z + v0.w + v1.x + v1.y + v1.z + v1.w;
    float sq = v0.x * v0.x + v0.y * v0.y + v0.z * v0.z + v0.w * v0.w +
               v1.x * v1.x + v1.y * v1.y + v1.z * v1.z + v1.w * v1.w;
#pragma unroll
    for (int msk = 1; msk < 64; msk <<= 1) {
        s += __shfl_xor(s, msk);
        sq += __shfl_xor(sq, msk);
    }
    float mu = s * (1.f / 512.f);
    float var = sq * (1.f / 512.f) - mu * mu;
    float rstd = rsqrtf(var + 1e-5f);
    float4 ga = *(const float4*)(g + lane * 8);
    float4 gb = *(const float4*)(g + lane * 8 + 4);
    float4 ba = *(const float4*)(b + lane * 8);
    float4 bb = *(const float4*)(b + lane * 8 + 4);
    float o0 = (v0.x - mu) * rstd * ga.x + ba.x;
    float o1 = (v0.y - mu) * rstd * ga.y + ba.y;
    float o2 = (v0.z - mu) * rstd * ga.z + ba.z;
    float o3 = (v0.w - mu) * rstd * ga.w + ba.w;
    float o4 = (v1.x - mu) * rstd * gb.x + bb.x;
    float o5 = (v1.y - mu) * rstd * gb.y + bb.y;
    float o6 = (v1.z - mu) * rstd * gb.z + bb.z;
    float o7 = (v1.w - mu) * rstd * gb.w + bb.w;
    float* orow = outf + (size_t)row * 512 + lane * 8;
    *(float4*)(orow) = make_float4(o0, o1, o2, o3);
    *(float4*)(orow + 4) = make_float4(o4, o5, o6, o7);
    if (outh) {
        h8 oh = {(_Float16)o0, (_Float16)o1, (_Float16)o2, (_Float16)o3,
                 (_Float16)o4, (_Float16)o5, (_Float16)o6, (_Float16)o7};
        *(h8*)(outh + (size_t)row * 512 + lane * 8) = oh;
    }
}

__global__ void k_tail(float* out) { out[(size_t)M_ * E_] = 0.f; }

// ---------------- launch ----------------
extern "C" void kernel_launch(void* const* d_in, const int* in_sizes, int n_in,
                              void* d_out, int out_size, void* d_ws, size_t ws_size,
                              hipStream_t stream) {
    const float* x   = (const float*)d_in[0];
    const float* Wq  = (const float*)d_in[1];
    const float* Wk  = (const float*)d_in[2];
    const float* Wv  = (const float*)d_in[3];
    const float* Wo  = (const float*)d_in[4];
    const float* bo  = (const float*)d_in[5];
    const float* g1  = (const float*)d_in[6];
    const float* b1  = (const float*)d_in[7];
    const float* W1  = (const float*)d_in[8];
    const float* bf1 = (const float*)d_in[9];
    const float* W2  = (const float*)d_in[10];
    const float* bf2 = (const float*)d_in[11];
    const float* g2  = (const float*)d_in[12];
    const float* b2  = (const float*)d_in[13];
    float* out = (float*)d_out;

    char* ws = (char*)d_ws;
    // byte offsets (all 256B-aligned); total ~78 MB
    _Float16* xh    = (_Float16*)(ws + 0);            // 8 MB; reused as out1h after QKV GEMM
    _Float16* wqkvT = (_Float16*)(ws + 8388608);      // 1.5 MB  [1536][512]
    _Float16* woT   = (_Float16*)(ws + 9961472);      // 0.5 MB
    _Float16* w1T   = (_Float16*)(ws + 10485760);     // 2 MB    [2048][512]
    _Float16* w2T   = (_Float16*)(ws + 12582912);     // 2 MB    [512][2048]
    _Float16* qb    = (_Float16*)(ws + 14680064);     // 8 MB; ff (32 MB) reuses qb..attnb
    _Float16* kb    = (_Float16*)(ws + 23068672);     // 8 MB
    _Float16* vtb   = (_Float16*)(ws + 31457280);     // 8 MB
    _Float16* attnb = (_Float16*)(ws + 39845888);     // 8 MB
    float*    h1    = (float*)(ws + 48234496);        // 16 MB fp32; reused as h2
    float*    out1f = (float*)(ws + 65011712);        // 16 MB fp32
    _Float16* out1h = xh;
    _Float16* ff    = qb;

    // stage 0: dtype conversion / weight transposes
    k_cvt<<<dim3(M_ * E_ / 1024), 256, 0, stream>>>(x, xh, M_ * E_);
    k_tr<<<dim3(512 * 512 / 256), 256, 0, stream>>>(Wq, wqkvT, 512, 512);
    k_tr<<<dim3(512 * 512 / 256), 256, 0, stream>>>(Wk, wqkvT + 512 * 512, 512, 512);
    k_tr<<<dim3(512 * 512 / 256), 256, 0, stream>>>(Wv, wqkvT + 1024 * 512, 512, 512);
    k_tr<<<dim3(512 * 512 / 256), 256, 0, stream>>>(Wo, woT, 512, 512);
    k_tr<<<dim3(512 * 2048 / 256), 256, 0, stream>>>(W1, w1T, 512, 2048);
    k_tr<<<dim3(2048 * 512 / 256), 256, 0, stream>>>(W2, w2T, 2048, 512);

    // QKV projection (fused, N=1536) with head-split scatter epilogue
    k_gemm<0><<<dim3(1536 / 128, M_ / 128), 256, 0, stream>>>(
        xh, wqkvT, M_, 1536, 512, nullptr, nullptr, nullptr, nullptr, qb, kb, vtb);

    // attention
    k_attn<<<dim3(N_ / 64, B_ * H_), 256, 0, stream>>>(qb, kb, vtb, attnb);

    // Wo projection + bias + residual(x) -> h1 (fp32)
    k_gemm<1><<<dim3(512 / 128, M_ / 128), 256, 0, stream>>>(
        attnb, woT, M_, 512, 512, bo, x, h1, nullptr, nullptr, nullptr, nullptr);

    // LN1 -> out1f (fp32) + out1h (f16)
    k_ln<<<dim3(M_ / 4), 256, 0, stream>>>(h1, g1, b1, out1f, out1h);

    // FFN1: relu(out1 @ W1 + bf1) -> ff (f16)
    k_gemm<2><<<dim3(2048 / 128, M_ / 128), 256, 0, stream>>>(
        out1h, w1T, M_, 2048, 512, bf1, nullptr, nullptr, ff, nullptr, nullptr, nullptr);

    // FFN2: ff @ W2 + bf2 + out1 -> h1 (reused as h2, fp32)
    k_gemm<1><<<dim3(512 / 128, M_ / 128), 256, 0, stream>>>(
        ff, w2T, M_, 512, 2048, bf2, out1f, h1, nullptr, nullptr, nullptr, nullptr);

    // LN2 -> d_out (fp32)
    k_ln<<<dim3(M_ / 4), 256, 0, stream>>>(h1, g2, b2, out, nullptr);

    // trailing scalar output (reference returns (out3, 0))
    k_tail<<<1, 1, 0, stream>>>(out);
}

// Round 2
// 270.302 us; speedup vs baseline: 1.0397x; 1.0397x over previous
//
#include <hip/hip_runtime.h>
#include <cstdint>
#include <cstddef>

// ---------------- types ----------------
typedef _Float16 h8 __attribute__((ext_vector_type(8)));
typedef _Float16 h4 __attribute__((ext_vector_type(4)));
typedef float    f32x4 __attribute__((ext_vector_type(4)));

constexpr int B_ = 8, N_ = 1024, E_ = 512, H_ = 8, D_ = 64, F_ = 2048;
constexpr int M_ = B_ * N_;   // 8192 rows
constexpr int HD_ = H_ * D_;  // 512

// q pre-scale: 1/sqrt(D) * log2(e)  (softmax done in base 2)
#define QSCALE2 0.18033688011112042f

#define GLOAD_LDS16(gp, lp)                                                        \
    __builtin_amdgcn_global_load_lds((const __attribute__((address_space(1))) void*)(gp), \
                                     (__attribute__((address_space(3))) void*)(lp), 16, 0, 0)

// ---------------- f32 -> f16 elementwise ----------------
__global__ void __launch_bounds__(256) k_cvt(const float* __restrict__ in,
                                             _Float16* __restrict__ out, int n) {
    int i = (blockIdx.x * 256 + threadIdx.x) * 4;
    if (i + 3 < n) {
        float4 v = *(const float4*)(in + i);
        h4 o = {(_Float16)v.x, (_Float16)v.y, (_Float16)v.z, (_Float16)v.w};
        *(h4*)(out + i) = o;
    }
}

// ---------------- transpose f32 [R][C] -> f16 [C][R] ----------------
__global__ void __launch_bounds__(256) k_tr(const float* __restrict__ in,
                                            _Float16* __restrict__ out, int R, int C) {
    int t = blockIdx.x * 256 + threadIdx.x;
    if (t < R * C) {
        int c = t / R, r = t - c * R;
        out[t] = (_Float16)in[r * C + c];  // out[c][r] = in[r][c]
    }
}

// ---------------- GEMM: C = A[M][K] * Bt[N][K]^T, f16 in, fp32 acc ----------------
// EPI 0: scatter to q/k/vT f16 buffers (QKV projection, N=1536); q gets QSCALE2
// EPI 1: outf = acc + bias[col] + res[row][col]  (fp32)
// EPI 2: outh = relu(acc + bias[col])            (f16)
template <int EPI>
__global__ void __launch_bounds__(256) k_gemm(
    const _Float16* __restrict__ A, const _Float16* __restrict__ Bt,
    int Mg, int Ng, int Kg,
    const float* __restrict__ bias, const float* __restrict__ res,
    float* __restrict__ outf, _Float16* __restrict__ outh,
    _Float16* __restrict__ qp, _Float16* __restrict__ kp, _Float16* __restrict__ vtp) {
    __shared__ alignas(16) _Float16 lA[128 * 64];
    __shared__ alignas(16) _Float16 lB[128 * 64];

    const int tid = threadIdx.x;
    const int lane = tid & 63;
    const int wid = tid >> 6;
    const int wr = wid >> 1, wc = wid & 1;      // 2x2 wave grid, each 64x64
    const int m0 = blockIdx.y * 128, n0 = blockIdx.x * 128;
    const int lrow = tid >> 3;                  // 0..31 rows per staging issue
    const int lcol = (tid & 7) * 8;             // 8 f16 per thread
    const int r16 = lane & 15, hseg = lane >> 4;

    f32x4 acc[4][4] = {};

    for (int k0 = 0; k0 < Kg; k0 += 64) {
        __syncthreads();
#pragma unroll
        for (int i = 0; i < 4; ++i) {
            const _Float16* gp = A + (size_t)(m0 + i * 32 + lrow) * Kg + k0 + lcol;
            GLOAD_LDS16(gp, lA + (i * 256 + tid) * 8);
        }
#pragma unroll
        for (int i = 0; i < 4; ++i) {
            const _Float16* gp = Bt + (size_t)(n0 + i * 32 + lrow) * Kg + k0 + lcol;
            GLOAD_LDS16(gp, lB + (i * 256 + tid) * 8);
        }
        __syncthreads();  // compiler drains vmcnt before barrier

#pragma unroll
        for (int kk = 0; kk < 2; ++kk) {
            h8 af[4], bf[4];
#pragma unroll
            for (int mi = 0; mi < 4; ++mi)
                af[mi] = *(const h8*)&lA[(wr * 64 + mi * 16 + r16) * 64 + kk * 32 + hseg * 8];
#pragma unroll
            for (int ni = 0; ni < 4; ++ni)
                bf[ni] = *(const h8*)&lB[(wc * 64 + ni * 16 + r16) * 64 + kk * 32 + hseg * 8];
#pragma unroll
            for (int mi = 0; mi < 4; ++mi)
#pragma unroll
                for (int ni = 0; ni < 4; ++ni)
                    acc[mi][ni] =
                        __builtin_amdgcn_mfma_f32_16x16x32_f16(af[mi], bf[ni], acc[mi][ni], 0, 0, 0);
        }
    }

    // epilogue: lane holds C[row = m0+wr*64+mi*16+hseg*4+r][col = n0+wc*64+ni*16+r16]
#pragma unroll
    for (int mi = 0; mi < 4; ++mi) {
#pragma unroll
        for (int ni = 0; ni < 4; ++ni) {
#pragma unroll
            for (int r = 0; r < 4; ++r) {
                int row = m0 + wr * 64 + mi * 16 + hseg * 4 + r;
                int col = n0 + wc * 64 + ni * 16 + r16;
                float v = acc[mi][ni][r];
                if constexpr (EPI == 0) {
                    int seg = col >> 9, cc = col & 511;
                    int h = cc >> 6, d = cc & 63;
                    int b = row >> 10, nn = row & 1023;
                    if (seg == 0)
                        qp[((b * 8 + h) * 1024 + nn) * 64 + d] = (_Float16)(v * QSCALE2);
                    else if (seg == 1)
                        kp[((b * 8 + h) * 1024 + nn) * 64 + d] = (_Float16)v;
                    else
                        vtp[((b * 8 + h) * 64 + d) * 1024 + nn] = (_Float16)v;
                } else if constexpr (EPI == 1) {
                    outf[(size_t)row * Ng + col] = v + bias[col] + res[(size_t)row * Ng + col];
                } else {
                    float t = v + bias[col];
                    outh[(size_t)row * Ng + col] = (_Float16)(t > 0.f ? t : 0.f);
                }
            }
        }
    }
}

// ---------------- flash attention: 1 block = (b,h) x 64 q-rows ----------------
// All LDS tiles XOR-swizzled: 16B slot col c at row r lives at c ^ (r&7).
// Staging keeps LDS dest linear and pre-swizzles the GLOBAL source (m173).
__global__ void __launch_bounds__(256) k_attn(const _Float16* __restrict__ q,
                                              const _Float16* __restrict__ k,
                                              const _Float16* __restrict__ vt,
                                              _Float16* __restrict__ attn) {
    __shared__ alignas(16) _Float16 lK[2][64 * 64];   // [key][d], swizzled
    __shared__ alignas(16) _Float16 lV[2][64 * 64];   // [d][key], swizzled
    __shared__ alignas(16) _Float16 lP[4][16 * 64];   // per-wave P tile, swizzled

    const int tid = threadIdx.x, lane = tid & 63, w = tid >> 6;
    const int bh = blockIdx.y;
    const int q0 = blockIdx.x * 64;
    const int r16 = lane & 15, hseg = lane >> 4;
    const size_t base = (size_t)bh * N_ * D_;

    // Q fragments (pre-scaled by QSCALE2 at QKV epilogue), held all kernel
    h8 qf[2];
#pragma unroll
    for (int kc = 0; kc < 2; ++kc)
        qf[kc] = *(const h8*)&q[base + (size_t)(q0 + w * 16 + r16) * 64 + kc * 32 + hseg * 8];

    // per-lane swizzled staging source: slot -> (row, c ^ (row&7))
    int srow[2], scsrc[2];
#pragma unroll
    for (int i = 0; i < 2; ++i) {
        int slot = i * 256 + tid;
        srow[i] = slot >> 3;
        scsrc[i] = (slot & 7) ^ (srow[i] & 7);
    }

    auto STAGE = [&](int buf, int kt) {
#pragma unroll
        for (int i = 0; i < 2; ++i)
            GLOAD_LDS16(k + base + kt * 4096 + srow[i] * 64 + scsrc[i] * 8,
                        &lK[buf][(i * 256 + tid) * 8]);
#pragma unroll
        for (int i = 0; i < 2; ++i)
            GLOAD_LDS16(vt + base + (size_t)srow[i] * N_ + kt * 64 + scsrc[i] * 8,
                        &lV[buf][(i * 256 + tid) * 8]);
    };

    float mrun[4], lrun[4];
    f32x4 oacc[4] = {};
#pragma unroll
    for (int r = 0; r < 4; ++r) { mrun[r] = -1e30f; lrun[r] = 0.f; }

    STAGE(0, 0);
    __syncthreads();  // drains vmcnt: buf0 ready

    for (int kt = 0; kt < N_ / 64; ++kt) {
        const int cur = kt & 1;
        if (kt + 1 < N_ / 64) STAGE(cur ^ 1, kt + 1);  // prefetch overlaps compute

        // S = (Q*scale2) K^T : 4 x (16q x 16key), K-dim = D = 64
        float sv[4][4];
#pragma unroll
        for (int t4 = 0; t4 < 4; ++t4) {
            f32x4 a = {};
            const int row = t4 * 16 + r16;
#pragma unroll
            for (int kc = 0; kc < 2; ++kc) {
                const int cw = kc * 4 + hseg;
                h8 kf = *(const h8*)&lK[cur][row * 64 + ((cw ^ (row & 7)) * 8)];
                a = __builtin_amdgcn_mfma_f32_16x16x32_f16(qf[kc], kf, a, 0, 0, 0);
            }
#pragma unroll
            for (int r = 0; r < 4; ++r) sv[t4][r] = a[r];
        }

        // online softmax in base-2, defer-max (T13, THR=8 -> P <= 256, f16-safe)
        float p[4][4];
#pragma unroll
        for (int r = 0; r < 4; ++r) {
            float mx = fmaxf(fmaxf(sv[0][r], sv[1][r]), fmaxf(sv[2][r], sv[3][r]));
#pragma unroll
            for (int msk = 1; msk < 16; msk <<= 1) mx = fmaxf(mx, __shfl_xor(mx, msk));
            if (mx > mrun[r] + 8.f) {
                float sc = exp2f(mrun[r] - mx);
                mrun[r] = mx;
                lrun[r] *= sc;
#pragma unroll
                for (int nf = 0; nf < 4; ++nf) oacc[nf][r] *= sc;
            }
            float rsum = 0.f;
#pragma unroll
            for (int t4 = 0; t4 < 4; ++t4) {
                p[t4][r] = exp2f(sv[t4][r] - mrun[r]);
                rsum += p[t4][r];
            }
#pragma unroll
            for (int msk = 1; msk < 16; msk <<= 1) rsum += __shfl_xor(rsum, msk);
            lrun[r] += rsum;
        }

        // P (D-layout) -> A-operand layout via per-wave LDS, swizzled
#pragma unroll
        for (int t4 = 0; t4 < 4; ++t4)
#pragma unroll
            for (int r = 0; r < 4; ++r) {
                const int rp = hseg * 4 + r;
                lP[w][rp * 64 + ((t4 * 16 + r16) ^ ((rp & 7) << 3))] = (_Float16)p[t4][r];
            }
        asm volatile("s_waitcnt lgkmcnt(0)" ::: "memory");  // wave-internal LDS fence

        h8 pa[2];
#pragma unroll
        for (int kc = 0; kc < 2; ++kc) {
            const int cw = kc * 4 + hseg;
            pa[kc] = *(const h8*)&lP[w][r16 * 64 + ((cw ^ (r16 & 7)) * 8)];
        }
#pragma unroll
        for (int nf = 0; nf < 4; ++nf) {
            const int row = nf * 16 + r16;
#pragma unroll
            for (int kc = 0; kc < 2; ++kc) {
                const int cw = kc * 4 + hseg;
                h8 vb = *(const h8*)&lV[cur][row * 64 + ((cw ^ (row & 7)) * 8)];
                oacc[nf] = __builtin_amdgcn_mfma_f32_16x16x32_f16(pa[kc], vb, oacc[nf], 0, 0, 0);
            }
        }
        __syncthreads();  // drains prefetch vmcnt + guards buffer swap
    }

    // write attn_out [M][HD] f16
    int b = bh >> 3, h = bh & 7;
#pragma unroll
    for (int r = 0; r < 4; ++r) {
        float inv = 1.f / lrun[r];
        int row = b * 1024 + q0 + w * 16 + hseg * 4 + r;
#pragma unroll
        for (int nf = 0; nf < 4; ++nf) {
            int col = h * 64 + nf * 16 + r16;
            attn[(size_t)row * 512 + col] = (_Float16)(oacc[nf][r] * inv);
        }
    }
}

// ---------------- layernorm: 1 wave per row of 512 ----------------
__global__ void __launch_bounds__(256) k_ln(const float* __restrict__ x,
                                            const float* __restrict__ g,
                                            const float* __restrict__ b,
                                            float* __restrict__ outf,
                                            _Float16* __restrict__ outh,
                                            float* __restrict__ tail) {
    int row = blockIdx.x * 4 + (threadIdx.x >> 6);
    int lane = threadIdx.x & 63;
    const float* xr = x + (size_t)row * 512;
    float4 v0 = *(const float4*)(xr + lane * 8);
    float4 v1 = *(const float4*)(xr + lane * 8 + 4);
    float s = v0.x + v0.y + v0.z + v0.w + v1.x + v1.y + v1.z + v1.w;
    float sq = v0.x * v0.x + v0.y * v0.y + v0.z * v0.z + v0.w * v0.w +
               v1.x * v1.x + v1.y * v1.y + v1.z * v1.z + v1.w * v1.w;
#pragma unroll
    for (int msk = 1; msk < 64; msk <<= 1) {
        s += __shfl_xor(s, msk);
        sq += __shfl_xor(sq, msk);
    }
    float mu = s * (1.f / 512.f);
    float var = sq * (1.f / 512.f) - mu * mu;
    float rstd = rsqrtf(var + 1e-5f);
    float4 ga = *(const float4*)(g + lane * 8);
    float4 gb = *(const float4*)(g + lane * 8 + 4);
    float4 ba = *(const float4*)(b + lane * 8);
    float4 bb = *(const float4*)(b + lane * 8 + 4);
    float o0 = (v0.x - mu) * rstd * ga.x + ba.x;
    float o1 = (v0.y - mu) * rstd * ga.y + ba.y;
    float o2 = (v0.z - mu) * rstd * ga.z + ba.z;
    float o3 = (v0.w - mu) * rstd * ga.w + ba.w;
    float o4 = (v1.x - mu) * rstd * gb.x + bb.x;
    float o5 = (v1.y - mu) * rstd * gb.y + bb.y;
    float o6 = (v1.z - mu) * rstd * gb.z + bb.z;
    float o7 = (v1.w - mu) * rstd * gb.w + bb.w;
    float* orow = outf + (size_t)row * 512 + lane * 8;
    *(float4*)(orow) = make_float4(o0, o1, o2, o3);
    *(float4*)(orow + 4) = make_float4(o4, o5, o6, o7);
    if (outh) {
        h8 oh = {(_Float16)o0, (_Float16)o1, (_Float16)o2, (_Float16)o3,
                 (_Float16)o4, (_Float16)o5, (_Float16)o6, (_Float16)o7};
        *(h8*)(outh + (size_t)row * 512 + lane * 8) = oh;
    }
    if (tail && blockIdx.x == 0 && threadIdx.x == 0) tail[0] = 0.f;
}

// ---------------- launch ----------------
extern "C" void kernel_launch(void* const* d_in, const int* in_sizes, int n_in,
                              void* d_out, int out_size, void* d_ws, size_t ws_size,
                              hipStream_t stream) {
    const float* x   = (const float*)d_in[0];
    const float* Wq  = (const float*)d_in[1];
    const float* Wk  = (const float*)d_in[2];
    const float* Wv  = (const float*)d_in[3];
    const float* Wo  = (const float*)d_in[4];
    const float* bo  = (const float*)d_in[5];
    const float* g1  = (const float*)d_in[6];
    const float* b1  = (const float*)d_in[7];
    const float* W1  = (const float*)d_in[8];
    const float* bf1 = (const float*)d_in[9];
    const float* W2  = (const float*)d_in[10];
    const float* bf2 = (const float*)d_in[11];
    const float* g2  = (const float*)d_in[12];
    const float* b2  = (const float*)d_in[13];
    float* out = (float*)d_out;

    char* ws = (char*)d_ws;
    // byte offsets (all 256B-aligned); total ~78 MB
    _Float16* xh    = (_Float16*)(ws + 0);            // 8 MB; reused as out1h after QKV GEMM
    _Float16* wqkvT = (_Float16*)(ws + 8388608);      // 1.5 MB  [1536][512]
    _Float16* woT   = (_Float16*)(ws + 9961472);      // 0.5 MB
    _Float16* w1T   = (_Float16*)(ws + 10485760);     // 2 MB    [2048][512]
    _Float16* w2T   = (_Float16*)(ws + 12582912);     // 2 MB    [512][2048]
    _Float16* qb    = (_Float16*)(ws + 14680064);     // 8 MB; ff (32 MB) reuses qb..attnb
    _Float16* kb    = (_Float16*)(ws + 23068672);     // 8 MB
    _Float16* vtb   = (_Float16*)(ws + 31457280);     // 8 MB
    _Float16* attnb = (_Float16*)(ws + 39845888);     // 8 MB
    float*    h1    = (float*)(ws + 48234496);        // 16 MB fp32; reused as h2
    float*    out1f = (float*)(ws + 65011712);        // 16 MB fp32
    _Float16* out1h = xh;
    _Float16* ff    = qb;

    // stage 0: dtype conversion / weight transposes
    k_cvt<<<dim3(M_ * E_ / 1024), 256, 0, stream>>>(x, xh, M_ * E_);
    k_tr<<<dim3(512 * 512 / 256), 256, 0, stream>>>(Wq, wqkvT, 512, 512);
    k_tr<<<dim3(512 * 512 / 256), 256, 0, stream>>>(Wk, wqkvT + 512 * 512, 512, 512);
    k_tr<<<dim3(512 * 512 / 256), 256, 0, stream>>>(Wv, wqkvT + 1024 * 512, 512, 512);
    k_tr<<<dim3(512 * 512 / 256), 256, 0, stream>>>(Wo, woT, 512, 512);
    k_tr<<<dim3(512 * 2048 / 256), 256, 0, stream>>>(W1, w1T, 512, 2048);
    k_tr<<<dim3(2048 * 512 / 256), 256, 0, stream>>>(W2, w2T, 2048, 512);

    // QKV projection (fused, N=1536) with head-split scatter epilogue
    k_gemm<0><<<dim3(1536 / 128, M_ / 128), 256, 0, stream>>>(
        xh, wqkvT, M_, 1536, 512, nullptr, nullptr, nullptr, nullptr, qb, kb, vtb);

    // attention
    k_attn<<<dim3(N_ / 64, B_ * H_), 256, 0, stream>>>(qb, kb, vtb, attnb);

    // Wo projection + bias + residual(x) -> h1 (fp32)
    k_gemm<1><<<dim3(512 / 128, M_ / 128), 256, 0, stream>>>(
        attnb, woT, M_, 512, 512, bo, x, h1, nullptr, nullptr, nullptr, nullptr);

    // LN1 -> out1f (fp32) + out1h (f16)
    k_ln<<<dim3(M_ / 4), 256, 0, stream>>>(h1, g1, b1, out1f, out1h, nullptr);

    // FFN1: relu(out1 @ W1 + bf1) -> ff (f16)
    k_gemm<2><<<dim3(2048 / 128, M_ / 128), 256, 0, stream>>>(
        out1h, w1T, M_, 2048, 512, bf1, nullptr, nullptr, ff, nullptr, nullptr, nullptr);

    // FFN2: ff @ W2 + bf2 + out1 -> h1 (reused as h2, fp32)
    k_gemm<1><<<dim3(512 / 128, M_ / 128), 256, 0, stream>>>(
        ff, w2T, M_, 512, 2048, bf2, out1f, h1, nullptr, nullptr, nullptr, nullptr);

    // LN2 -> d_out (fp32) + trailing scalar (reference returns (out3, 0))
    k_ln<<<dim3(M_ / 4), 256, 0, stream>>>(h1, g2, b2, out, nullptr, out + (size_t)M_ * E_);
}

// Round 3
// 236.121 us; speedup vs baseline: 1.1902x; 1.1448x over previous
//
#include <hip/hip_runtime.h>
#include <cstdint>
#include <cstddef>

// ---------------- types ----------------
typedef _Float16 h8 __attribute__((ext_vector_type(8)));
typedef _Float16 h4 __attribute__((ext_vector_type(4)));
typedef float    f32x4 __attribute__((ext_vector_type(4)));

constexpr int B_ = 8, N_ = 1024, E_ = 512, H_ = 8, D_ = 64, F_ = 2048;
constexpr int M_ = B_ * N_;   // 8192 rows
constexpr int HD_ = H_ * D_;  // 512

// q pre-scale: 1/sqrt(D) * log2(e)  (softmax done in base 2)
#define QSCALE2 0.18033688011112042f

#define GLOAD_LDS16(gp, lp)                                                        \
    __builtin_amdgcn_global_load_lds((const __attribute__((address_space(1))) void*)(gp), \
                                     (__attribute__((address_space(3))) void*)(lp), 16, 0, 0)

// ---------------- f32 -> f16 elementwise ----------------
__global__ void __launch_bounds__(256) k_cvt(const float* __restrict__ in,
                                             _Float16* __restrict__ out, int n) {
    int i = (blockIdx.x * 256 + threadIdx.x) * 4;
    if (i + 3 < n) {
        float4 v = *(const float4*)(in + i);
        h4 o = {(_Float16)v.x, (_Float16)v.y, (_Float16)v.z, (_Float16)v.w};
        *(h4*)(out + i) = o;
    }
}

// ---------------- transpose f32 [R][C] -> f16 [C][R] ----------------
__global__ void __launch_bounds__(256) k_tr(const float* __restrict__ in,
                                            _Float16* __restrict__ out, int R, int C) {
    int t = blockIdx.x * 256 + threadIdx.x;
    if (t < R * C) {
        int c = t / R, r = t - c * R;
        out[t] = (_Float16)in[r * C + c];  // out[c][r] = in[r][c]
    }
}

// ---------------- GEMM: C = A[M][K] * Bt[N][K]^T, f16 in, fp32 acc ----------------
// EPI 0: scatter to q/k/vT f16 buffers (QKV projection, N=1536); q gets QSCALE2
// EPI 1: outf = acc + bias[col] + res[row][col]  (fp32)
// EPI 2: outh = relu(acc + bias[col])            (f16)
template <int EPI>
__global__ void __launch_bounds__(256) k_gemm(
    const _Float16* __restrict__ A, const _Float16* __restrict__ Bt,
    int Mg, int Ng, int Kg,
    const float* __restrict__ bias, const float* __restrict__ res,
    float* __restrict__ outf, _Float16* __restrict__ outh,
    _Float16* __restrict__ qp, _Float16* __restrict__ kp, _Float16* __restrict__ vtp) {
    __shared__ alignas(16) _Float16 lA[128 * 64];
    __shared__ alignas(16) _Float16 lB[128 * 64];

    const int tid = threadIdx.x;
    const int lane = tid & 63;
    const int wid = tid >> 6;
    const int wr = wid >> 1, wc = wid & 1;      // 2x2 wave grid, each 64x64
    const int m0 = blockIdx.y * 128, n0 = blockIdx.x * 128;
    const int lrow = tid >> 3;                  // 0..31 rows per staging issue
    const int lcol = (tid & 7) * 8;             // 8 f16 per thread
    const int r16 = lane & 15, hseg = lane >> 4;

    f32x4 acc[4][4] = {};

    for (int k0 = 0; k0 < Kg; k0 += 64) {
        __syncthreads();
#pragma unroll
        for (int i = 0; i < 4; ++i) {
            const _Float16* gp = A + (size_t)(m0 + i * 32 + lrow) * Kg + k0 + lcol;
            GLOAD_LDS16(gp, lA + (i * 256 + tid) * 8);
        }
#pragma unroll
        for (int i = 0; i < 4; ++i) {
            const _Float16* gp = Bt + (size_t)(n0 + i * 32 + lrow) * Kg + k0 + lcol;
            GLOAD_LDS16(gp, lB + (i * 256 + tid) * 8);
        }
        __syncthreads();  // compiler drains vmcnt before barrier

#pragma unroll
        for (int kk = 0; kk < 2; ++kk) {
            h8 af[4], bf[4];
#pragma unroll
            for (int mi = 0; mi < 4; ++mi)
                af[mi] = *(const h8*)&lA[(wr * 64 + mi * 16 + r16) * 64 + kk * 32 + hseg * 8];
#pragma unroll
            for (int ni = 0; ni < 4; ++ni)
                bf[ni] = *(const h8*)&lB[(wc * 64 + ni * 16 + r16) * 64 + kk * 32 + hseg * 8];
#pragma unroll
            for (int mi = 0; mi < 4; ++mi)
#pragma unroll
                for (int ni = 0; ni < 4; ++ni)
                    acc[mi][ni] =
                        __builtin_amdgcn_mfma_f32_16x16x32_f16(af[mi], bf[ni], acc[mi][ni], 0, 0, 0);
        }
    }

    // epilogue: lane holds C[row = m0+wr*64+mi*16+hseg*4+r][col = n0+wc*64+ni*16+r16]
#pragma unroll
    for (int mi = 0; mi < 4; ++mi) {
#pragma unroll
        for (int ni = 0; ni < 4; ++ni) {
#pragma unroll
            for (int r = 0; r < 4; ++r) {
                int row = m0 + wr * 64 + mi * 16 + hseg * 4 + r;
                int col = n0 + wc * 64 + ni * 16 + r16;
                float v = acc[mi][ni][r];
                if constexpr (EPI == 0) {
                    int seg = col >> 9, cc = col & 511;
                    int h = cc >> 6, d = cc & 63;
                    int b = row >> 10, nn = row & 1023;
                    if (seg == 0)
                        qp[((b * 8 + h) * 1024 + nn) * 64 + d] = (_Float16)(v * QSCALE2);
                    else if (seg == 1)
                        kp[((b * 8 + h) * 1024 + nn) * 64 + d] = (_Float16)v;
                    else
                        vtp[((b * 8 + h) * 64 + d) * 1024 + nn] = (_Float16)v;
                } else if constexpr (EPI == 1) {
                    outf[(size_t)row * Ng + col] = v + bias[col] + res[(size_t)row * Ng + col];
                } else {
                    float t = v + bias[col];
                    outh[(size_t)row * Ng + col] = (_Float16)(t > 0.f ? t : 0.f);
                }
            }
        }
    }
}

// ---------------- flash attention: 1 block = (b,h) x 64 q-rows ----------------
// Swapped QK^T (T12 mechanism): S-tile = mfma(K, Q) so q-index = lane&15 and each
// lane holds 16 S-values of ONE q-row -> softmax reduction is in-lane + 2 shfl.
// All LDS tiles XOR-swizzled; staging pre-swizzles the GLOBAL source (m173).
__global__ void __launch_bounds__(256) k_attn(const _Float16* __restrict__ q,
                                              const _Float16* __restrict__ k,
                                              const _Float16* __restrict__ vt,
                                              _Float16* __restrict__ attn) {
    __shared__ alignas(16) _Float16 lK[2][64 * 64];   // [key][d], swizzled
    __shared__ alignas(16) _Float16 lV[2][64 * 64];   // [d][key], swizzled
    __shared__ alignas(16) _Float16 lP[4][16 * 64];   // per-wave P tile, swizzled

    const int tid = threadIdx.x, lane = tid & 63, w = tid >> 6;
    const int bh = blockIdx.y;
    const int q0 = blockIdx.x * 64;
    const int r16 = lane & 15, hseg = lane >> 4;
    const size_t base = (size_t)bh * N_ * D_;

    // Q fragments (pre-scaled by QSCALE2 at QKV epilogue), held all kernel
    h8 qf[2];
#pragma unroll
    for (int kc = 0; kc < 2; ++kc)
        qf[kc] = *(const h8*)&q[base + (size_t)(q0 + w * 16 + r16) * 64 + kc * 32 + hseg * 8];

    // per-lane swizzled staging source: slot -> (row, c ^ (row&7))
    int srow[2], scsrc[2];
#pragma unroll
    for (int i = 0; i < 2; ++i) {
        int slot = i * 256 + tid;
        srow[i] = slot >> 3;
        scsrc[i] = (slot & 7) ^ (srow[i] & 7);
    }

    auto STAGE = [&](int buf, int kt) {
#pragma unroll
        for (int i = 0; i < 2; ++i)
            GLOAD_LDS16(k + base + kt * 4096 + srow[i] * 64 + scsrc[i] * 8,
                        &lK[buf][(i * 256 + tid) * 8]);
#pragma unroll
        for (int i = 0; i < 2; ++i)
            GLOAD_LDS16(vt + base + (size_t)srow[i] * N_ + kt * 64 + scsrc[i] * 8,
                        &lV[buf][(i * 256 + tid) * 8]);
    };

    // softmax state for q-row (q0 + w*16 + r16): lane-local scalars
    float mrun = -1e30f, lrun = 0.f;
    f32x4 oacc[4] = {};  // O[q = hseg*4+r][d = nf*16+r16]

    const int pswz = (r16 & 7) * 8;  // lP element-index XOR per q-row

    STAGE(0, 0);
    __syncthreads();  // drains vmcnt: buf0 ready

    for (int kt = 0; kt < N_ / 64; ++kt) {
        const int cur = kt & 1;
        if (kt + 1 < N_ / 64) STAGE(cur ^ 1, kt + 1);  // prefetch overlaps compute

        // S tiles swapped: sv[t4][r] = S[key = t4*16 + hseg*4 + r][q = r16]
        float sv[4][4];
#pragma unroll
        for (int t4 = 0; t4 < 4; ++t4) {
            f32x4 a = {};
            const int row = t4 * 16 + r16;  // key row for the A-operand fragment
#pragma unroll
            for (int kc = 0; kc < 2; ++kc) {
                const int cw = kc * 4 + hseg;
                h8 kf = *(const h8*)&lK[cur][row * 64 + ((cw ^ (row & 7)) * 8)];
                a = __builtin_amdgcn_mfma_f32_16x16x32_f16(kf, qf[kc], a, 0, 0, 0);
            }
#pragma unroll
            for (int r = 0; r < 4; ++r) sv[t4][r] = a[r];
        }

        // in-lane max over 16 values + 2 cross-lane steps
        float mx = sv[0][0];
#pragma unroll
        for (int t4 = 0; t4 < 4; ++t4)
#pragma unroll
            for (int r = 0; r < 4; ++r) mx = fmaxf(mx, sv[t4][r]);
        mx = fmaxf(mx, __shfl_xor(mx, 16));
        mx = fmaxf(mx, __shfl_xor(mx, 32));

        // defer-max (T13, THR=8 in log2 units -> P <= 256, f16-safe)
        if (__any(mx > mrun + 8.f)) {
            float mnew = fmaxf(mrun, mx);
            float sc = exp2f(mrun - mnew);
            mrun = mnew;
            lrun *= sc;
            // broadcast sc to C-row layout (q' = hseg*4+r lives in lane q')
#pragma unroll
            for (int r = 0; r < 4; ++r) {
                float scq = __shfl(sc, hseg * 4 + r);
#pragma unroll
                for (int nf = 0; nf < 4; ++nf) oacc[nf][r] *= scq;
            }
        }

        // P = exp2(S - m), in-lane sum + 2 cross-lane steps
        float p[4][4];
        float rsum = 0.f;
#pragma unroll
        for (int t4 = 0; t4 < 4; ++t4) {
#pragma unroll
            for (int r = 0; r < 4; ++r) {
                p[t4][r] = exp2f(sv[t4][r] - mrun);
                rsum += p[t4][r];
            }
        }
        rsum += __shfl_xor(rsum, 16);
        rsum += __shfl_xor(rsum, 32);
        lrun += rsum;

        // P -> A-operand layout via per-wave LDS: lP[q=r16][key], swizzled.
        // Lane's 4 values per t4 are consecutive keys -> one b64 write each.
#pragma unroll
        for (int t4 = 0; t4 < 4; ++t4) {
            h4 pv = {(_Float16)p[t4][0], (_Float16)p[t4][1],
                     (_Float16)p[t4][2], (_Float16)p[t4][3]};
            *(h4*)&lP[w][r16 * 64 + ((t4 * 16 + hseg * 4) ^ pswz)] = pv;
        }
        asm volatile("s_waitcnt lgkmcnt(0)" ::: "memory");  // wave-internal LDS fence

        h8 pa[2];
#pragma unroll
        for (int kc = 0; kc < 2; ++kc)
            pa[kc] = *(const h8*)&lP[w][r16 * 64 + ((kc * 32 + hseg * 8) ^ pswz)];
#pragma unroll
        for (int nf = 0; nf < 4; ++nf) {
            const int row = nf * 16 + r16;
#pragma unroll
            for (int kc = 0; kc < 2; ++kc) {
                const int cw = kc * 4 + hseg;
                h8 vb = *(const h8*)&lV[cur][row * 64 + ((cw ^ (row & 7)) * 8)];
                oacc[nf] = __builtin_amdgcn_mfma_f32_16x16x32_f16(pa[kc], vb, oacc[nf], 0, 0, 0);
            }
        }
        __syncthreads();  // drains prefetch vmcnt + guards buffer swap
    }

    // write attn_out [M][HD] f16; 1/l broadcast to C-row layout
    float rlin = 1.f / lrun;
    int b = bh >> 3, h = bh & 7;
#pragma unroll
    for (int r = 0; r < 4; ++r) {
        float inv = __shfl(rlin, hseg * 4 + r);
        int row = b * 1024 + q0 + w * 16 + hseg * 4 + r;
#pragma unroll
        for (int nf = 0; nf < 4; ++nf) {
            int col = h * 64 + nf * 16 + r16;
            attn[(size_t)row * 512 + col] = (_Float16)(oacc[nf][r] * inv);
        }
    }
}

// ---------------- layernorm: 1 wave per row of 512 ----------------
__global__ void __launch_bounds__(256) k_ln(const float* __restrict__ x,
                                            const float* __restrict__ g,
                                            const float* __restrict__ b,
                                            float* __restrict__ outf,
                                            _Float16* __restrict__ outh,
                                            float* __restrict__ tail) {
    int row = blockIdx.x * 4 + (threadIdx.x >> 6);
    int lane = threadIdx.x & 63;
    const float* xr = x + (size_t)row * 512;
    float4 v0 = *(const float4*)(xr + lane * 8);
    float4 v1 = *(const float4*)(xr + lane * 8 + 4);
    float s = v0.x + v0.y + v0.z + v0.w + v1.x + v1.y + v1.z + v1.w;
    float sq = v0.x * v0.x + v0.y * v0.y + v0.z * v0.z + v0.w * v0.w +
               v1.x * v1.x + v1.y * v1.y + v1.z * v1.z + v1.w * v1.w;
#pragma unroll
    for (int msk = 1; msk < 64; msk <<= 1) {
        s += __shfl_xor(s, msk);
        sq += __shfl_xor(sq, msk);
    }
    float mu = s * (1.f / 512.f);
    float var = sq * (1.f / 512.f) - mu * mu;
    float rstd = rsqrtf(var + 1e-5f);
    float4 ga = *(const float4*)(g + lane * 8);
    float4 gb = *(const float4*)(g + lane * 8 + 4);
    float4 ba = *(const float4*)(b + lane * 8);
    float4 bb = *(const float4*)(b + lane * 8 + 4);
    float o0 = (v0.x - mu) * rstd * ga.x + ba.x;
    float o1 = (v0.y - mu) * rstd * ga.y + ba.y;
    float o2 = (v0.z - mu) * rstd * ga.z + ba.z;
    float o3 = (v0.w - mu) * rstd * ga.w + ba.w;
    float o4 = (v1.x - mu) * rstd * gb.x + bb.x;
    float o5 = (v1.y - mu) * rstd * gb.y + bb.y;
    float o6 = (v1.z - mu) * rstd * gb.z + bb.z;
    float o7 = (v1.w - mu) * rstd * gb.w + bb.w;
    float* orow = outf + (size_t)row * 512 + lane * 8;
    *(float4*)(orow) = make_float4(o0, o1, o2, o3);
    *(float4*)(orow + 4) = make_float4(o4, o5, o6, o7);
    if (outh) {
        h8 oh = {(_Float16)o0, (_Float16)o1, (_Float16)o2, (_Float16)o3,
                 (_Float16)o4, (_Float16)o5, (_Float16)o6, (_Float16)o7};
        *(h8*)(outh + (size_t)row * 512 + lane * 8) = oh;
    }
    if (tail && blockIdx.x == 0 && threadIdx.x == 0) tail[0] = 0.f;
}

// ---------------- launch ----------------
extern "C" void kernel_launch(void* const* d_in, const int* in_sizes, int n_in,
                              void* d_out, int out_size, void* d_ws, size_t ws_size,
                              hipStream_t stream) {
    const float* x   = (const float*)d_in[0];
    const float* Wq  = (const float*)d_in[1];
    const float* Wk  = (const float*)d_in[2];
    const float* Wv  = (const float*)d_in[3];
    const float* Wo  = (const float*)d_in[4];
    const float* bo  = (const float*)d_in[5];
    const float* g1  = (const float*)d_in[6];
    const float* b1  = (const float*)d_in[7];
    const float* W1  = (const float*)d_in[8];
    const float* bf1 = (const float*)d_in[9];
    const float* W2  = (const float*)d_in[10];
    const float* bf2 = (const float*)d_in[11];
    const float* g2  = (const float*)d_in[12];
    const float* b2  = (const float*)d_in[13];
    float* out = (float*)d_out;

    char* ws = (char*)d_ws;
    // byte offsets (all 256B-aligned); total ~78 MB
    _Float16* xh    = (_Float16*)(ws + 0);            // 8 MB; reused as out1h after QKV GEMM
    _Float16* wqkvT = (_Float16*)(ws + 8388608);      // 1.5 MB  [1536][512]
    _Float16* woT   = (_Float16*)(ws + 9961472);      // 0.5 MB
    _Float16* w1T   = (_Float16*)(ws + 10485760);     // 2 MB    [2048][512]
    _Float16* w2T   = (_Float16*)(ws + 12582912);     // 2 MB    [512][2048]
    _Float16* qb    = (_Float16*)(ws + 14680064);     // 8 MB; ff (32 MB) reuses qb..attnb
    _Float16* kb    = (_Float16*)(ws + 23068672);     // 8 MB
    _Float16* vtb   = (_Float16*)(ws + 31457280);     // 8 MB
    _Float16* attnb = (_Float16*)(ws + 39845888);     // 8 MB
    float*    h1    = (float*)(ws + 48234496);        // 16 MB fp32; reused as h2
    float*    out1f = (float*)(ws + 65011712);        // 16 MB fp32
    _Float16* out1h = xh;
    _Float16* ff    = qb;

    // stage 0: dtype conversion / weight transposes
    k_cvt<<<dim3(M_ * E_ / 1024), 256, 0, stream>>>(x, xh, M_ * E_);
    k_tr<<<dim3(512 * 512 / 256), 256, 0, stream>>>(Wq, wqkvT, 512, 512);
    k_tr<<<dim3(512 * 512 / 256), 256, 0, stream>>>(Wk, wqkvT + 512 * 512, 512, 512);
    k_tr<<<dim3(512 * 512 / 256), 256, 0, stream>>>(Wv, wqkvT + 1024 * 512, 512, 512);
    k_tr<<<dim3(512 * 512 / 256), 256, 0, stream>>>(Wo, woT, 512, 512);
    k_tr<<<dim3(512 * 2048 / 256), 256, 0, stream>>>(W1, w1T, 512, 2048);
    k_tr<<<dim3(2048 * 512 / 256), 256, 0, stream>>>(W2, w2T, 2048, 512);

    // QKV projection (fused, N=1536) with head-split scatter epilogue
    k_gemm<0><<<dim3(1536 / 128, M_ / 128), 256, 0, stream>>>(
        xh, wqkvT, M_, 1536, 512, nullptr, nullptr, nullptr, nullptr, qb, kb, vtb);

    // attention
    k_attn<<<dim3(N_ / 64, B_ * H_), 256, 0, stream>>>(qb, kb, vtb, attnb);

    // Wo projection + bias + residual(x) -> h1 (fp32)
    k_gemm<1><<<dim3(512 / 128, M_ / 128), 256, 0, stream>>>(
        attnb, woT, M_, 512, 512, bo, x, h1, nullptr, nullptr, nullptr, nullptr);

    // LN1 -> out1f (fp32) + out1h (f16)
    k_ln<<<dim3(M_ / 4), 256, 0, stream>>>(h1, g1, b1, out1f, out1h, nullptr);

    // FFN1: relu(out1 @ W1 + bf1) -> ff (f16)
    k_gemm<2><<<dim3(2048 / 128, M_ / 128), 256, 0, stream>>>(
        out1h, w1T, M_, 2048, 512, bf1, nullptr, nullptr, ff, nullptr, nullptr, nullptr);

    // FFN2: ff @ W2 + bf2 + out1 -> h1 (reused as h2, fp32)
    k_gemm<1><<<dim3(512 / 128, M_ / 128), 256, 0, stream>>>(
        ff, w2T, M_, 512, 2048, bf2, out1f, h1, nullptr, nullptr, nullptr, nullptr);

    // LN2 -> d_out (fp32) + trailing scalar (reference returns (out3, 0))
    k_ln<<<dim3(M_ / 4), 256, 0, stream>>>(h1, g2, b2, out, nullptr, out + (size_t)M_ * E_);
}

// Round 4
// 202.706 us; speedup vs baseline: 1.3864x; 1.1648x over previous
//
#include <hip/hip_runtime.h>
#include <cstdint>
#include <cstddef>

// ---------------- types ----------------
typedef _Float16 h8 __attribute__((ext_vector_type(8)));
typedef _Float16 h4 __attribute__((ext_vector_type(4)));
typedef float    f32x4 __attribute__((ext_vector_type(4)));

constexpr int B_ = 8, N_ = 1024, E_ = 512, H_ = 8, D_ = 64, F_ = 2048;
constexpr int M_ = B_ * N_;   // 8192 rows
constexpr int HD_ = H_ * D_;  // 512

// q pre-scale: 1/sqrt(D) * log2(e)  (softmax done in base 2)
#define QSCALE2 0.18033688011112042f

#define GLOAD_LDS16(gp, lp)                                                        \
    __builtin_amdgcn_global_load_lds((const __attribute__((address_space(1))) void*)(gp), \
                                     (__attribute__((address_space(3))) void*)(lp), 16, 0, 0)

// ---------------- f32 -> f16 elementwise ----------------
__global__ void __launch_bounds__(256) k_cvt(const float* __restrict__ in,
                                             _Float16* __restrict__ out, int n) {
    int i = (blockIdx.x * 256 + threadIdx.x) * 4;
    if (i + 3 < n) {
        float4 v = *(const float4*)(in + i);
        h4 o = {(_Float16)v.x, (_Float16)v.y, (_Float16)v.z, (_Float16)v.w};
        *(h4*)(out + i) = o;
    }
}

// ---------------- fused 6-way weight transpose, LDS 32x32 tiles ----------------
// z: 0..3 = Wq,Wk,Wv,Wo (512x512, 256 tiles); 4..7 = W1 quarters; 8..11 = W2 quarters
__global__ void __launch_bounds__(256) k_tr6(
    const float* __restrict__ Wq, const float* __restrict__ Wk,
    const float* __restrict__ Wv, const float* __restrict__ Wo,
    const float* __restrict__ W1, const float* __restrict__ W2,
    _Float16* __restrict__ oqkv, _Float16* __restrict__ oo,
    _Float16* __restrict__ o1, _Float16* __restrict__ o2) {
    const float* in;
    _Float16* out;
    int R, C, gt = blockIdx.x;
    switch (blockIdx.z) {
        case 0: in = Wq; out = oqkv;              R = 512;  C = 512;  break;
        case 1: in = Wk; out = oqkv + 512 * 512;  R = 512;  C = 512;  break;
        case 2: in = Wv; out = oqkv + 1024 * 512; R = 512;  C = 512;  break;
        case 3: in = Wo; out = oo;                R = 512;  C = 512;  break;
        default:
            if (blockIdx.z < 8) { in = W1; out = o1; R = 512;  C = 2048; gt += (blockIdx.z - 4) * 256; }
            else                { in = W2; out = o2; R = 2048; C = 512;  gt += (blockIdx.z - 8) * 256; }
    }
    const int ctiles = C >> 5;
    const int ty = gt / ctiles, tx = gt - ty * ctiles;
    const int r0 = ty * 32, c0 = tx * 32;
    __shared__ float lt[32][33];
    const int rr = threadIdx.x >> 3, cq = threadIdx.x & 7;
    float4 v = *(const float4*)&in[(size_t)(r0 + rr) * C + c0 + cq * 4];
    lt[rr][cq * 4 + 0] = v.x; lt[rr][cq * 4 + 1] = v.y;
    lt[rr][cq * 4 + 2] = v.z; lt[rr][cq * 4 + 3] = v.w;
    __syncthreads();
    h4 o = {(_Float16)lt[cq * 4 + 0][rr], (_Float16)lt[cq * 4 + 1][rr],
            (_Float16)lt[cq * 4 + 2][rr], (_Float16)lt[cq * 4 + 3][rr]};
    *(h4*)&out[(size_t)(c0 + rr) * R + r0 + cq * 4] = o;
}

// ---------------- GEMM: C = A[M][K] * Bt[N][K]^T, f16 in, fp32 acc ----------------
// Double-buffered 2-phase schedule (T3-min): prefetch K-step t+1 before computing t.
// EPI 0: scatter to q/k/vT f16 buffers (QKV, N=1536); q gets QSCALE2; V via LDS transpose
// EPI 1: outf = acc + bias[col] + res[row][col]  (fp32)
// EPI 2: outh = relu(acc + bias[col])            (f16)
template <int EPI>
__global__ void __launch_bounds__(256) k_gemm(
    const _Float16* __restrict__ A, const _Float16* __restrict__ Bt,
    int Mg, int Ng, int Kg,
    const float* __restrict__ bias, const float* __restrict__ res,
    float* __restrict__ outf, _Float16* __restrict__ outh,
    _Float16* __restrict__ qp, _Float16* __restrict__ kp, _Float16* __restrict__ vtp) {
    __shared__ alignas(16) _Float16 lA[2][128 * 64];
    __shared__ alignas(16) _Float16 lB[2][128 * 64];

    const int tid = threadIdx.x;
    const int lane = tid & 63;
    const int wid = tid >> 6;
    const int wr = wid >> 1, wc = wid & 1;      // 2x2 wave grid, each 64x64
    const int m0 = blockIdx.y * 128, n0 = blockIdx.x * 128;
    const int lrow = tid >> 3;                  // 0..31 rows per staging issue
    const int lcol = (tid & 7) * 8;             // 8 f16 per thread
    const int r16 = lane & 15, hseg = lane >> 4;

    auto STAGE = [&](int buf, int k0) {
#pragma unroll
        for (int i = 0; i < 4; ++i)
            GLOAD_LDS16(A + (size_t)(m0 + i * 32 + lrow) * Kg + k0 + lcol,
                        &lA[buf][(i * 256 + tid) * 8]);
#pragma unroll
        for (int i = 0; i < 4; ++i)
            GLOAD_LDS16(Bt + (size_t)(n0 + i * 32 + lrow) * Kg + k0 + lcol,
                        &lB[buf][(i * 256 + tid) * 8]);
    };

    f32x4 acc[4][4] = {};
    const int nt = Kg >> 6;

    STAGE(0, 0);
    __syncthreads();  // vmcnt(0)+barrier: buf0 ready

    for (int t = 0; t < nt; ++t) {
        const int cur = t & 1;
        if (t + 1 < nt) STAGE(cur ^ 1, (t + 1) << 6);  // prefetch overlaps compute

#pragma unroll
        for (int kk = 0; kk < 2; ++kk) {
            h8 af[4], bf[4];
#pragma unroll
            for (int mi = 0; mi < 4; ++mi)
                af[mi] = *(const h8*)&lA[cur][(wr * 64 + mi * 16 + r16) * 64 + kk * 32 + hseg * 8];
#pragma unroll
            for (int ni = 0; ni < 4; ++ni)
                bf[ni] = *(const h8*)&lB[cur][(wc * 64 + ni * 16 + r16) * 64 + kk * 32 + hseg * 8];
#pragma unroll
            for (int mi = 0; mi < 4; ++mi)
#pragma unroll
                for (int ni = 0; ni < 4; ++ni)
                    acc[mi][ni] =
                        __builtin_amdgcn_mfma_f32_16x16x32_f16(af[mi], bf[ni], acc[mi][ni], 0, 0, 0);
        }
        __syncthreads();  // drains prefetch vmcnt + read lgkmcnt, guards buffer swap
    }

    // epilogue: lane holds C[row = m0+wr*64+mi*16+hseg*4+r][col = n0+wc*64+ni*16+r16]
    if constexpr (EPI == 0) {
        if (n0 >= 1024) {
            // V block: transpose C-tile through LDS (lA is free), coalesced h8 stores.
            _Float16* lC = &lA[0][0];  // [128 cols][128 rows] f16, 16B-slot XOR swizzle
#pragma unroll
            for (int mi = 0; mi < 4; ++mi) {
                const int r0 = wr * 64 + mi * 16 + hseg * 4;
#pragma unroll
                for (int ni = 0; ni < 4; ++ni) {
                    const int c = wc * 64 + ni * 16 + r16;
                    h4 pv = {(_Float16)acc[mi][ni][0], (_Float16)acc[mi][ni][1],
                             (_Float16)acc[mi][ni][2], (_Float16)acc[mi][ni][3]};
                    *(h4*)&lC[c * 128 + (((r0 >> 4) ^ (c & 7)) << 4) + (r0 & 15)] = pv;
                }
            }
            __syncthreads();
            const int c = tid >> 1;
            const int half = tid & 1;
            const int b = m0 >> 10, nn0 = m0 & 1023;
            _Float16* gdst = vtp + ((size_t)(b * 512 + (n0 - 1024) + c)) * 1024 + nn0 + half * 64;
#pragma unroll
            for (int j = 0; j < 8; ++j) {
                const int r = half * 64 + j * 8;
                h8 v = *(const h8*)&lC[c * 128 + (((r >> 4) ^ (c & 7)) << 4) + (r & 15)];
                *(h8*)&gdst[j * 8] = v;
            }
        } else {
#pragma unroll
            for (int mi = 0; mi < 4; ++mi)
#pragma unroll
                for (int ni = 0; ni < 4; ++ni)
#pragma unroll
                    for (int r = 0; r < 4; ++r) {
                        int row = m0 + wr * 64 + mi * 16 + hseg * 4 + r;
                        int col = n0 + wc * 64 + ni * 16 + r16;
                        float v = acc[mi][ni][r];
                        int cc = col & 511;
                        int h = cc >> 6, d = cc & 63;
                        int b = row >> 10, nn = row & 1023;
                        if (col < 512)
                            qp[((b * 8 + h) * 1024 + nn) * 64 + d] = (_Float16)(v * QSCALE2);
                        else
                            kp[((b * 8 + h) * 1024 + nn) * 64 + d] = (_Float16)v;
                    }
        }
    } else {
#pragma unroll
        for (int mi = 0; mi < 4; ++mi)
#pragma unroll
            for (int ni = 0; ni < 4; ++ni)
#pragma unroll
                for (int r = 0; r < 4; ++r) {
                    int row = m0 + wr * 64 + mi * 16 + hseg * 4 + r;
                    int col = n0 + wc * 64 + ni * 16 + r16;
                    float v = acc[mi][ni][r];
                    if constexpr (EPI == 1) {
                        outf[(size_t)row * Ng + col] = v + bias[col] + res[(size_t)row * Ng + col];
                    } else {
                        float t = v + bias[col];
                        outh[(size_t)row * Ng + col] = (_Float16)(t > 0.f ? t : 0.f);
                    }
                }
    }
}

// ---------------- flash attention: 1 block = (b,h) x 64 q-rows ----------------
// Swapped QK^T (T12 mechanism): S-tile = mfma(K, Q) so q-index = lane&15 and each
// lane holds 16 S-values of ONE q-row -> softmax reduction is in-lane + 2 shfl.
// All LDS tiles XOR-swizzled; staging pre-swizzles the GLOBAL source (m173).
__global__ void __launch_bounds__(256) k_attn(const _Float16* __restrict__ q,
                                              const _Float16* __restrict__ k,
                                              const _Float16* __restrict__ vt,
                                              _Float16* __restrict__ attn) {
    __shared__ alignas(16) _Float16 lK[2][64 * 64];   // [key][d], swizzled
    __shared__ alignas(16) _Float16 lV[2][64 * 64];   // [d][key], swizzled
    __shared__ alignas(16) _Float16 lP[4][16 * 64];   // per-wave P tile, swizzled

    const int tid = threadIdx.x, lane = tid & 63, w = tid >> 6;
    const int bh = blockIdx.y;
    const int q0 = blockIdx.x * 64;
    const int r16 = lane & 15, hseg = lane >> 4;
    const size_t base = (size_t)bh * N_ * D_;

    // Q fragments (pre-scaled by QSCALE2 at QKV epilogue), held all kernel
    h8 qf[2];
#pragma unroll
    for (int kc = 0; kc < 2; ++kc)
        qf[kc] = *(const h8*)&q[base + (size_t)(q0 + w * 16 + r16) * 64 + kc * 32 + hseg * 8];

    // per-lane swizzled staging source: slot -> (row, c ^ (row&7))
    int srow[2], scsrc[2];
#pragma unroll
    for (int i = 0; i < 2; ++i) {
        int slot = i * 256 + tid;
        srow[i] = slot >> 3;
        scsrc[i] = (slot & 7) ^ (srow[i] & 7);
    }

    auto STAGE = [&](int buf, int kt) {
#pragma unroll
        for (int i = 0; i < 2; ++i)
            GLOAD_LDS16(k + base + kt * 4096 + srow[i] * 64 + scsrc[i] * 8,
                        &lK[buf][(i * 256 + tid) * 8]);
#pragma unroll
        for (int i = 0; i < 2; ++i)
            GLOAD_LDS16(vt + base + (size_t)srow[i] * N_ + kt * 64 + scsrc[i] * 8,
                        &lV[buf][(i * 256 + tid) * 8]);
    };

    // softmax state for q-row (q0 + w*16 + r16): lane-local scalars
    float mrun = -1e30f, lrun = 0.f;
    f32x4 oacc[4] = {};  // O[q = hseg*4+r][d = nf*16+r16]

    const int pswz = (r16 & 7) * 8;  // lP element-index XOR per q-row

    STAGE(0, 0);
    __syncthreads();  // drains vmcnt: buf0 ready

    for (int kt = 0; kt < N_ / 64; ++kt) {
        const int cur = kt & 1;
        if (kt + 1 < N_ / 64) STAGE(cur ^ 1, kt + 1);  // prefetch overlaps compute

        // S tiles swapped: sv[t4][r] = S[key = t4*16 + hseg*4 + r][q = r16]
        float sv[4][4];
#pragma unroll
        for (int t4 = 0; t4 < 4; ++t4) {
            f32x4 a = {};
            const int row = t4 * 16 + r16;  // key row for the A-operand fragment
#pragma unroll
            for (int kc = 0; kc < 2; ++kc) {
                const int cw = kc * 4 + hseg;
                h8 kf = *(const h8*)&lK[cur][row * 64 + ((cw ^ (row & 7)) * 8)];
                a = __builtin_amdgcn_mfma_f32_16x16x32_f16(kf, qf[kc], a, 0, 0, 0);
            }
#pragma unroll
            for (int r = 0; r < 4; ++r) sv[t4][r] = a[r];
        }

        // in-lane max over 16 values + 2 cross-lane steps
        float mx = sv[0][0];
#pragma unroll
        for (int t4 = 0; t4 < 4; ++t4)
#pragma unroll
            for (int r = 0; r < 4; ++r) mx = fmaxf(mx, sv[t4][r]);
        mx = fmaxf(mx, __shfl_xor(mx, 16));
        mx = fmaxf(mx, __shfl_xor(mx, 32));

        // defer-max (T13, THR=8 in log2 units -> P <= 256, f16-safe)
        if (__any(mx > mrun + 8.f)) {
            float mnew = fmaxf(mrun, mx);
            float sc = exp2f(mrun - mnew);
            mrun = mnew;
            lrun *= sc;
            // broadcast sc to C-row layout (q' = hseg*4+r lives in lane q')
#pragma unroll
            for (int r = 0; r < 4; ++r) {
                float scq = __shfl(sc, hseg * 4 + r);
#pragma unroll
                for (int nf = 0; nf < 4; ++nf) oacc[nf][r] *= scq;
            }
        }

        // P = exp2(S - m), in-lane sum + 2 cross-lane steps
        float p[4][4];
        float rsum = 0.f;
#pragma unroll
        for (int t4 = 0; t4 < 4; ++t4) {
#pragma unroll
            for (int r = 0; r < 4; ++r) {
                p[t4][r] = exp2f(sv[t4][r] - mrun);
                rsum += p[t4][r];
            }
        }
        rsum += __shfl_xor(rsum, 16);
        rsum += __shfl_xor(rsum, 32);
        lrun += rsum;

        // P -> A-operand layout via per-wave LDS: lP[q=r16][key], swizzled.
        // Lane's 4 values per t4 are consecutive keys -> one b64 write each.
#pragma unroll
        for (int t4 = 0; t4 < 4; ++t4) {
            h4 pv = {(_Float16)p[t4][0], (_Float16)p[t4][1],
                     (_Float16)p[t4][2], (_Float16)p[t4][3]};
            *(h4*)&lP[w][r16 * 64 + ((t4 * 16 + hseg * 4) ^ pswz)] = pv;
        }
        asm volatile("s_waitcnt lgkmcnt(0)" ::: "memory");  // wave-internal LDS fence

        h8 pa[2];
#pragma unroll
        for (int kc = 0; kc < 2; ++kc)
            pa[kc] = *(const h8*)&lP[w][r16 * 64 + ((kc * 32 + hseg * 8) ^ pswz)];
#pragma unroll
        for (int nf = 0; nf < 4; ++nf) {
            const int row = nf * 16 + r16;
#pragma unroll
            for (int kc = 0; kc < 2; ++kc) {
                const int cw = kc * 4 + hseg;
                h8 vb = *(const h8*)&lV[cur][row * 64 + ((cw ^ (row & 7)) * 8)];
                oacc[nf] = __builtin_amdgcn_mfma_f32_16x16x32_f16(pa[kc], vb, oacc[nf], 0, 0, 0);
            }
        }
        __syncthreads();  // drains prefetch vmcnt + guards buffer swap
    }

    // write attn_out [M][HD] f16; 1/l broadcast to C-row layout
    float rlin = 1.f / lrun;
    int b = bh >> 3, h = bh & 7;
#pragma unroll
    for (int r = 0; r < 4; ++r) {
        float inv = __shfl(rlin, hseg * 4 + r);
        int row = b * 1024 + q0 + w * 16 + hseg * 4 + r;
#pragma unroll
        for (int nf = 0; nf < 4; ++nf) {
            int col = h * 64 + nf * 16 + r16;
            attn[(size_t)row * 512 + col] = (_Float16)(oacc[nf][r] * inv);
        }
    }
}

// ---------------- layernorm: 1 wave per row of 512 ----------------
__global__ void __launch_bounds__(256) k_ln(const float* __restrict__ x,
                                            const float* __restrict__ g,
                                            const float* __restrict__ b,
                                            float* __restrict__ outf,
                                            _Float16* __restrict__ outh,
                                            float* __restrict__ tail) {
    int row = blockIdx.x * 4 + (threadIdx.x >> 6);
    int lane = threadIdx.x & 63;
    const float* xr = x + (size_t)row * 512;
    float4 v0 = *(const float4*)(xr + lane * 8);
    float4 v1 = *(const float4*)(xr + lane * 8 + 4);
    float s = v0.x + v0.y + v0.z + v0.w + v1.x + v1.y + v1.z + v1.w;
    float sq = v0.x * v0.x + v0.y * v0.y + v0.z * v0.z + v0.w * v0.w +
               v1.x * v1.x + v1.y * v1.y + v1.z * v1.z + v1.w * v1.w;
#pragma unroll
    for (int msk = 1; msk < 64; msk <<= 1) {
        s += __shfl_xor(s, msk);
        sq += __shfl_xor(sq, msk);
    }
    float mu = s * (1.f / 512.f);
    float var = sq * (1.f / 512.f) - mu * mu;
    float rstd = rsqrtf(var + 1e-5f);
    float4 ga = *(const float4*)(g + lane * 8);
    float4 gb = *(const float4*)(g + lane * 8 + 4);
    float4 ba = *(const float4*)(b + lane * 8);
    float4 bb = *(const float4*)(b + lane * 8 + 4);
    float o0 = (v0.x - mu) * rstd * ga.x + ba.x;
    float o1 = (v0.y - mu) * rstd * ga.y + ba.y;
    float o2 = (v0.z - mu) * rstd * ga.z + ba.z;
    float o3 = (v0.w - mu) * rstd * ga.w + ba.w;
    float o4 = (v1.x - mu) * rstd * gb.x + bb.x;
    float o5 = (v1.y - mu) * rstd * gb.y + bb.y;
    float o6 = (v1.z - mu) * rstd * gb.z + bb.z;
    float o7 = (v1.w - mu) * rstd * gb.w + bb.w;
    float* orow = outf + (size_t)row * 512 + lane * 8;
    *(float4*)(orow) = make_float4(o0, o1, o2, o3);
    *(float4*)(orow + 4) = make_float4(o4, o5, o6, o7);
    if (outh) {
        h8 oh = {(_Float16)o0, (_Float16)o1, (_Float16)o2, (_Float16)o3,
                 (_Float16)o4, (_Float16)o5, (_Float16)o6, (_Float16)o7};
        *(h8*)(outh + (size_t)row * 512 + lane * 8) = oh;
    }
    if (tail && blockIdx.x == 0 && threadIdx.x == 0) tail[0] = 0.f;
}

// ---------------- launch ----------------
extern "C" void kernel_launch(void* const* d_in, const int* in_sizes, int n_in,
                              void* d_out, int out_size, void* d_ws, size_t ws_size,
                              hipStream_t stream) {
    const float* x   = (const float*)d_in[0];
    const float* Wq  = (const float*)d_in[1];
    const float* Wk  = (const float*)d_in[2];
    const float* Wv  = (const float*)d_in[3];
    const float* Wo  = (const float*)d_in[4];
    const float* bo  = (const float*)d_in[5];
    const float* g1  = (const float*)d_in[6];
    const float* b1  = (const float*)d_in[7];
    const float* W1  = (const float*)d_in[8];
    const float* bf1 = (const float*)d_in[9];
    const float* W2  = (const float*)d_in[10];
    const float* bf2 = (const float*)d_in[11];
    const float* g2  = (const float*)d_in[12];
    const float* b2  = (const float*)d_in[13];
    float* out = (float*)d_out;

    char* ws = (char*)d_ws;
    // byte offsets (all 256B-aligned); total ~78 MB
    _Float16* xh    = (_Float16*)(ws + 0);            // 8 MB; reused as out1h after QKV GEMM
    _Float16* wqkvT = (_Float16*)(ws + 8388608);      // 1.5 MB  [1536][512]
    _Float16* woT   = (_Float16*)(ws + 9961472);      // 0.5 MB
    _Float16* w1T   = (_Float16*)(ws + 10485760);     // 2 MB    [2048][512]
    _Float16* w2T   = (_Float16*)(ws + 12582912);     // 2 MB    [512][2048]
    _Float16* qb    = (_Float16*)(ws + 14680064);     // 8 MB; ff (32 MB) reuses qb..attnb
    _Float16* kb    = (_Float16*)(ws + 23068672);     // 8 MB
    _Float16* vtb   = (_Float16*)(ws + 31457280);     // 8 MB
    _Float16* attnb = (_Float16*)(ws + 39845888);     // 8 MB
    float*    h1    = (float*)(ws + 48234496);        // 16 MB fp32; reused as h2
    float*    out1f = (float*)(ws + 65011712);        // 16 MB fp32
    _Float16* out1h = xh;
    _Float16* ff    = qb;

    // stage 0: dtype conversion + fused weight transposes
    k_cvt<<<dim3(M_ * E_ / 1024), 256, 0, stream>>>(x, xh, M_ * E_);
    k_tr6<<<dim3(256, 1, 12), 256, 0, stream>>>(Wq, Wk, Wv, Wo, W1, W2,
                                                wqkvT, woT, w1T, w2T);

    // QKV projection (fused, N=1536) with head-split scatter epilogue
    k_gemm<0><<<dim3(1536 / 128, M_ / 128), 256, 0, stream>>>(
        xh, wqkvT, M_, 1536, 512, nullptr, nullptr, nullptr, nullptr, qb, kb, vtb);

    // attention
    k_attn<<<dim3(N_ / 64, B_ * H_), 256, 0, stream>>>(qb, kb, vtb, attnb);

    // Wo projection + bias + residual(x) -> h1 (fp32)
    k_gemm<1><<<dim3(512 / 128, M_ / 128), 256, 0, stream>>>(
        attnb, woT, M_, 512, 512, bo, x, h1, nullptr, nullptr, nullptr, nullptr);

    // LN1 -> out1f (fp32) + out1h (f16)
    k_ln<<<dim3(M_ / 4), 256, 0, stream>>>(h1, g1, b1, out1f, out1h, nullptr);

    // FFN1: relu(out1 @ W1 + bf1) -> ff (f16)
    k_gemm<2><<<dim3(2048 / 128, M_ / 128), 256, 0, stream>>>(
        out1h, w1T, M_, 2048, 512, bf1, nullptr, nullptr, ff, nullptr, nullptr, nullptr);

    // FFN2: ff @ W2 + bf2 + out1 -> h1 (reused as h2, fp32)
    k_gemm<1><<<dim3(512 / 128, M_ / 128), 256, 0, stream>>>(
        ff, w2T, M_, 512, 2048, bf2, out1f, h1, nullptr, nullptr, nullptr, nullptr);

    // LN2 -> d_out (fp32) + trailing scalar (reference returns (out3, 0))
    k_ln<<<dim3(M_ / 4), 256, 0, stream>>>(h1, g2, b2, out, nullptr, out + (size_t)M_ * E_);
}

// Round 5
// 162.379 us; speedup vs baseline: 1.7307x; 1.2483x over previous
//
#include <hip/hip_runtime.h>
#include <cstdint>
#include <cstddef>

// ---------------- types ----------------
typedef _Float16 h8 __attribute__((ext_vector_type(8)));
typedef _Float16 h4 __attribute__((ext_vector_type(4)));
typedef float    f32x4 __attribute__((ext_vector_type(4)));

constexpr int B_ = 8, N_ = 1024, E_ = 512, H_ = 8, D_ = 64, F_ = 2048;
constexpr int M_ = B_ * N_;   // 8192 rows
constexpr int HD_ = H_ * D_;  // 512

// q pre-scale: 1/sqrt(D) * log2(e)  (softmax done in base 2)
#define QSCALE2 0.18033688011112042f

#define GLOAD_LDS16(gp, lp)                                                        \
    __builtin_amdgcn_global_load_lds((const __attribute__((address_space(1))) void*)(gp), \
                                     (__attribute__((address_space(3))) void*)(lp), 16, 0, 0)

// ---------------- f32 -> f16 elementwise ----------------
__global__ void __launch_bounds__(256) k_cvt(const float* __restrict__ in,
                                             _Float16* __restrict__ out, int n) {
    int i = (blockIdx.x * 256 + threadIdx.x) * 4;
    if (i + 3 < n) {
        float4 v = *(const float4*)(in + i);
        h4 o = {(_Float16)v.x, (_Float16)v.y, (_Float16)v.z, (_Float16)v.w};
        *(h4*)(out + i) = o;
    }
}

// ---------------- fused 6-way weight transpose, LDS 32x32 tiles ----------------
__global__ void __launch_bounds__(256) k_tr6(
    const float* __restrict__ Wq, const float* __restrict__ Wk,
    const float* __restrict__ Wv, const float* __restrict__ Wo,
    const float* __restrict__ W1, const float* __restrict__ W2,
    _Float16* __restrict__ oqkv, _Float16* __restrict__ oo,
    _Float16* __restrict__ o1, _Float16* __restrict__ o2) {
    const float* in;
    _Float16* out;
    int R, C, gt = blockIdx.x;
    switch (blockIdx.z) {
        case 0: in = Wq; out = oqkv;              R = 512;  C = 512;  break;
        case 1: in = Wk; out = oqkv + 512 * 512;  R = 512;  C = 512;  break;
        case 2: in = Wv; out = oqkv + 1024 * 512; R = 512;  C = 512;  break;
        case 3: in = Wo; out = oo;                R = 512;  C = 512;  break;
        default:
            if (blockIdx.z < 8) { in = W1; out = o1; R = 512;  C = 2048; gt += (blockIdx.z - 4) * 256; }
            else                { in = W2; out = o2; R = 2048; C = 512;  gt += (blockIdx.z - 8) * 256; }
    }
    const int ctiles = C >> 5;
    const int ty = gt / ctiles, tx = gt - ty * ctiles;
    const int r0 = ty * 32, c0 = tx * 32;
    __shared__ float lt[32][33];
    const int rr = threadIdx.x >> 3, cq = threadIdx.x & 7;
    float4 v = *(const float4*)&in[(size_t)(r0 + rr) * C + c0 + cq * 4];
    lt[rr][cq * 4 + 0] = v.x; lt[rr][cq * 4 + 1] = v.y;
    lt[rr][cq * 4 + 2] = v.z; lt[rr][cq * 4 + 3] = v.w;
    __syncthreads();
    h4 o = {(_Float16)lt[cq * 4 + 0][rr], (_Float16)lt[cq * 4 + 1][rr],
            (_Float16)lt[cq * 4 + 2][rr], (_Float16)lt[cq * 4 + 3][rr]};
    *(h4*)&out[(size_t)(c0 + rr) * R + r0 + cq * 4] = o;
}

// ---------------- GEMM: C = A[M][K] * Bt[N][K]^T, f16 in, fp32 acc ----------------
// BM=64 fixed; BN templated (64 or 128). 4 waves in 2x2 grid, wave tile 32 x BN/2.
// 1-D grid with XCD-aware decode: xcd = bid&7 owns 16 contiguous m-panels (T1),
// so A-panels are fetched once per XCD and L2-reused across all n-tiles.
// LDS XOR-swizzled (T2): staging pre-swizzles GLOBAL source, reads XOR back.
// 2-phase double-buffered prefetch (T3-min).
// EPI 0: QKV scatter (q *= QSCALE2, k direct, v transposed via LDS)
// EPI 1: outf = acc + bias[col] + res[row][col]  (fp32)
// EPI 2: outh = relu(acc + bias[col])            (f16)
template <int BN, int EPI>
__global__ void __launch_bounds__(256) k_gemm(
    const _Float16* __restrict__ A, const _Float16* __restrict__ Bt,
    int Mg, int Ng, int Kg,
    const float* __restrict__ bias, const float* __restrict__ res,
    float* __restrict__ outf, _Float16* __restrict__ outh,
    _Float16* __restrict__ qp, _Float16* __restrict__ kp, _Float16* __restrict__ vtp) {
    constexpr int WN = BN / 2;       // wave tile cols
    constexpr int NI = WN / 16;      // n-frags per wave
    __shared__ alignas(16) _Float16 lA[2][64 * 64];
    __shared__ alignas(16) _Float16 lB[2][BN * 64];

    const int tid = threadIdx.x;
    const int lane = tid & 63;
    const int wid = tid >> 6;
    const int wr = wid >> 1, wc = wid & 1;
    const int r16 = lane & 15, hseg = lane >> 4;

    // XCD-aware tile decode (M tiles = 128 always: 16 per XCD)
    const int bid = blockIdx.x;
    const int xcd = bid & 7;
    const int rem = bid >> 3;
    const int tx = rem >> 4, tyl = rem & 15;
    const int m0 = (xcd * 16 + tyl) * 64;
    const int n0 = tx * BN;

    auto STAGE = [&](int buf, int k0) {
#pragma unroll
        for (int i = 0; i < 2; ++i) {
            const int slot = i * 256 + tid, row = slot >> 3;
            const int cs = (slot & 7) ^ (row & 7);
            GLOAD_LDS16(A + (size_t)(m0 + row) * Kg + k0 + cs * 8, &lA[buf][slot * 8]);
        }
#pragma unroll
        for (int i = 0; i < BN / 32; ++i) {
            const int slot = i * 256 + tid, row = slot >> 3;
            const int cs = (slot & 7) ^ (row & 7);
            GLOAD_LDS16(Bt + (size_t)(n0 + row) * Kg + k0 + cs * 8, &lB[buf][slot * 8]);
        }
    };

    f32x4 acc[2][NI] = {};
    const int nt = Kg >> 6;

    STAGE(0, 0);
    __syncthreads();  // vmcnt(0)+barrier: buf0 ready

    for (int t = 0; t < nt; ++t) {
        const int cur = t & 1;
        if (t + 1 < nt) STAGE(cur ^ 1, (t + 1) << 6);  // prefetch overlaps compute

#pragma unroll
        for (int kk = 0; kk < 2; ++kk) {
            h8 af[2], bf[NI];
#pragma unroll
            for (int mi = 0; mi < 2; ++mi) {
                const int row = wr * 32 + mi * 16 + r16;
                af[mi] = *(const h8*)&lA[cur][row * 64 + (((kk * 4 + hseg) ^ (row & 7)) * 8)];
            }
#pragma unroll
            for (int ni = 0; ni < NI; ++ni) {
                const int row = wc * WN + ni * 16 + r16;
                bf[ni] = *(const h8*)&lB[cur][row * 64 + (((kk * 4 + hseg) ^ (row & 7)) * 8)];
            }
#pragma unroll
            for (int mi = 0; mi < 2; ++mi)
#pragma unroll
                for (int ni = 0; ni < NI; ++ni)
                    acc[mi][ni] =
                        __builtin_amdgcn_mfma_f32_16x16x32_f16(af[mi], bf[ni], acc[mi][ni], 0, 0, 0);
        }
        __syncthreads();  // drains prefetch vmcnt + read lgkmcnt, guards buffer swap
    }

    // epilogue: lane holds C[row = m0+wr*32+mi*16+hseg*4+r][col = n0+wc*WN+ni*16+r16]
    if constexpr (EPI == 0) {
        if (n0 >= 1024) {
            // V block: transpose 64x128 C-tile through LDS (lA: 128 cols x 64 rows).
            // Col c, 16B slot s lives at s ^ (c&7).
            _Float16* lC = &lA[0][0];
#pragma unroll
            for (int mi = 0; mi < 2; ++mi) {
                const int r0 = wr * 32 + mi * 16 + hseg * 4;
                const int s = r0 >> 3, ro = r0 & 7;
#pragma unroll
                for (int ni = 0; ni < NI; ++ni) {
                    const int c = wc * WN + ni * 16 + r16;
                    h4 pv = {(_Float16)acc[mi][ni][0], (_Float16)acc[mi][ni][1],
                             (_Float16)acc[mi][ni][2], (_Float16)acc[mi][ni][3]};
                    *(h4*)&lC[c * 64 + ((s ^ (c & 7)) << 3) + ro] = pv;
                }
            }
            __syncthreads();
            const int c = tid >> 1, half = tid & 1;
            const int b = m0 >> 10, nn0 = m0 & 1023;
            _Float16* gdst =
                vtp + ((size_t)(b * 512 + (n0 - 1024) + c)) * 1024 + nn0 + half * 32;
#pragma unroll
            for (int j = 0; j < 4; ++j) {
                const int s = half * 4 + j;
                h8 v = *(const h8*)&lC[c * 64 + ((s ^ (c & 7)) << 3)];
                *(h8*)&gdst[j * 8] = v;
            }
        } else {
#pragma unroll
            for (int mi = 0; mi < 2; ++mi)
#pragma unroll
                for (int ni = 0; ni < NI; ++ni)
#pragma unroll
                    for (int r = 0; r < 4; ++r) {
                        int row = m0 + wr * 32 + mi * 16 + hseg * 4 + r;
                        int col = n0 + wc * WN + ni * 16 + r16;
                        float v = acc[mi][ni][r];
                        int cc = col & 511;
                        int h = cc >> 6, d = cc & 63;
                        int b = row >> 10, nn = row & 1023;
                        if (col < 512)
                            qp[((b * 8 + h) * 1024 + nn) * 64 + d] = (_Float16)(v * QSCALE2);
                        else
                            kp[((b * 8 + h) * 1024 + nn) * 64 + d] = (_Float16)v;
                    }
        }
    } else {
#pragma unroll
        for (int mi = 0; mi < 2; ++mi)
#pragma unroll
            for (int ni = 0; ni < NI; ++ni)
#pragma unroll
                for (int r = 0; r < 4; ++r) {
                    int row = m0 + wr * 32 + mi * 16 + hseg * 4 + r;
                    int col = n0 + wc * WN + ni * 16 + r16;
                    float v = acc[mi][ni][r];
                    if constexpr (EPI == 1) {
                        outf[(size_t)row * Ng + col] = v + bias[col] + res[(size_t)row * Ng + col];
                    } else {
                        float t = v + bias[col];
                        outh[(size_t)row * Ng + col] = (_Float16)(t > 0.f ? t : 0.f);
                    }
                }
    }
}

// ---------------- flash attention: 1 block = (b,h) x 64 q-rows ----------------
// Swapped QK^T (T12 mechanism) + XOR-swizzled LDS + 2-phase prefetch.
// 1-D grid with XCD decode: each XCD owns 8 bh values -> K/V L2-resident per XCD.
__global__ void __launch_bounds__(256) k_attn(const _Float16* __restrict__ q,
                                              const _Float16* __restrict__ k,
                                              const _Float16* __restrict__ vt,
                                              _Float16* __restrict__ attn) {
    __shared__ alignas(16) _Float16 lK[2][64 * 64];   // [key][d], swizzled
    __shared__ alignas(16) _Float16 lV[2][64 * 64];   // [d][key], swizzled
    __shared__ alignas(16) _Float16 lP[4][16 * 64];   // per-wave P tile, swizzled

    const int tid = threadIdx.x, lane = tid & 63, w = tid >> 6;
    const int bid = blockIdx.x;
    const int xcd = bid & 7, rem = bid >> 3;
    const int bh = xcd * 8 + (rem & 7);
    const int q0 = (rem >> 3) * 64;
    const int r16 = lane & 15, hseg = lane >> 4;
    const size_t base = (size_t)bh * N_ * D_;

    // Q fragments (pre-scaled by QSCALE2 at QKV epilogue), held all kernel
    h8 qf[2];
#pragma unroll
    for (int kc = 0; kc < 2; ++kc)
        qf[kc] = *(const h8*)&q[base + (size_t)(q0 + w * 16 + r16) * 64 + kc * 32 + hseg * 8];

    // per-lane swizzled staging source: slot -> (row, c ^ (row&7))
    int srow[2], scsrc[2];
#pragma unroll
    for (int i = 0; i < 2; ++i) {
        int slot = i * 256 + tid;
        srow[i] = slot >> 3;
        scsrc[i] = (slot & 7) ^ (srow[i] & 7);
    }

    auto STAGE = [&](int buf, int kt) {
#pragma unroll
        for (int i = 0; i < 2; ++i)
            GLOAD_LDS16(k + base + kt * 4096 + srow[i] * 64 + scsrc[i] * 8,
                        &lK[buf][(i * 256 + tid) * 8]);
#pragma unroll
        for (int i = 0; i < 2; ++i)
            GLOAD_LDS16(vt + base + (size_t)srow[i] * N_ + kt * 64 + scsrc[i] * 8,
                        &lV[buf][(i * 256 + tid) * 8]);
    };

    // softmax state for q-row (q0 + w*16 + r16): lane-local scalars
    float mrun = -1e30f, lrun = 0.f;
    f32x4 oacc[4] = {};  // O[q = hseg*4+r][d = nf*16+r16]

    const int pswz = (r16 & 7) * 8;  // lP element-index XOR per q-row

    STAGE(0, 0);
    __syncthreads();  // drains vmcnt: buf0 ready

    for (int kt = 0; kt < N_ / 64; ++kt) {
        const int cur = kt & 1;
        if (kt + 1 < N_ / 64) STAGE(cur ^ 1, kt + 1);  // prefetch overlaps compute

        // S tiles swapped: sv[t4][r] = S[key = t4*16 + hseg*4 + r][q = r16]
        float sv[4][4];
#pragma unroll
        for (int t4 = 0; t4 < 4; ++t4) {
            f32x4 a = {};
            const int row = t4 * 16 + r16;  // key row for the A-operand fragment
#pragma unroll
            for (int kc = 0; kc < 2; ++kc) {
                const int cw = kc * 4 + hseg;
                h8 kf = *(const h8*)&lK[cur][row * 64 + ((cw ^ (row & 7)) * 8)];
                a = __builtin_amdgcn_mfma_f32_16x16x32_f16(kf, qf[kc], a, 0, 0, 0);
            }
#pragma unroll
            for (int r = 0; r < 4; ++r) sv[t4][r] = a[r];
        }

        // in-lane max over 16 values + 2 cross-lane steps
        float mx = sv[0][0];
#pragma unroll
        for (int t4 = 0; t4 < 4; ++t4)
#pragma unroll
            for (int r = 0; r < 4; ++r) mx = fmaxf(mx, sv[t4][r]);
        mx = fmaxf(mx, __shfl_xor(mx, 16));
        mx = fmaxf(mx, __shfl_xor(mx, 32));

        // defer-max (T13, THR=8 in log2 units -> P <= 256, f16-safe)
        if (__any(mx > mrun + 8.f)) {
            float mnew = fmaxf(mrun, mx);
            float sc = exp2f(mrun - mnew);
            mrun = mnew;
            lrun *= sc;
            // broadcast sc to C-row layout (q' = hseg*4+r lives in lane q')
#pragma unroll
            for (int r = 0; r < 4; ++r) {
                float scq = __shfl(sc, hseg * 4 + r);
#pragma unroll
                for (int nf = 0; nf < 4; ++nf) oacc[nf][r] *= scq;
            }
        }

        // P = exp2(S - m), in-lane sum + 2 cross-lane steps
        float p[4][4];
        float rsum = 0.f;
#pragma unroll
        for (int t4 = 0; t4 < 4; ++t4) {
#pragma unroll
            for (int r = 0; r < 4; ++r) {
                p[t4][r] = exp2f(sv[t4][r] - mrun);
                rsum += p[t4][r];
            }
        }
        rsum += __shfl_xor(rsum, 16);
        rsum += __shfl_xor(rsum, 32);
        lrun += rsum;

        // P -> A-operand layout via per-wave LDS: lP[q=r16][key], swizzled.
#pragma unroll
        for (int t4 = 0; t4 < 4; ++t4) {
            h4 pv = {(_Float16)p[t4][0], (_Float16)p[t4][1],
                     (_Float16)p[t4][2], (_Float16)p[t4][3]};
            *(h4*)&lP[w][r16 * 64 + ((t4 * 16 + hseg * 4) ^ pswz)] = pv;
        }
        asm volatile("s_waitcnt lgkmcnt(0)" ::: "memory");  // wave-internal LDS fence

        h8 pa[2];
#pragma unroll
        for (int kc = 0; kc < 2; ++kc)
            pa[kc] = *(const h8*)&lP[w][r16 * 64 + ((kc * 32 + hseg * 8) ^ pswz)];
#pragma unroll
        for (int nf = 0; nf < 4; ++nf) {
            const int row = nf * 16 + r16;
#pragma unroll
            for (int kc = 0; kc < 2; ++kc) {
                const int cw = kc * 4 + hseg;
                h8 vb = *(const h8*)&lV[cur][row * 64 + ((cw ^ (row & 7)) * 8)];
                oacc[nf] = __builtin_amdgcn_mfma_f32_16x16x32_f16(pa[kc], vb, oacc[nf], 0, 0, 0);
            }
        }
        __syncthreads();  // drains prefetch vmcnt + guards buffer swap
    }

    // write attn_out [M][HD] f16; 1/l broadcast to C-row layout
    float rlin = 1.f / lrun;
    int b = bh >> 3, h = bh & 7;
#pragma unroll
    for (int r = 0; r < 4; ++r) {
        float inv = __shfl(rlin, hseg * 4 + r);
        int row = b * 1024 + q0 + w * 16 + hseg * 4 + r;
#pragma unroll
        for (int nf = 0; nf < 4; ++nf) {
            int col = h * 64 + nf * 16 + r16;
            attn[(size_t)row * 512 + col] = (_Float16)(oacc[nf][r] * inv);
        }
    }
}

// ---------------- layernorm: 1 wave per row of 512 ----------------
__global__ void __launch_bounds__(256) k_ln(const float* __restrict__ x,
                                            const float* __restrict__ g,
                                            const float* __restrict__ b,
                                            float* __restrict__ outf,
                                            _Float16* __restrict__ outh,
                                            float* __restrict__ tail) {
    int row = blockIdx.x * 4 + (threadIdx.x >> 6);
    int lane = threadIdx.x & 63;
    const float* xr = x + (size_t)row * 512;
    float4 v0 = *(const float4*)(xr + lane * 8);
    float4 v1 = *(const float4*)(xr + lane * 8 + 4);
    float s = v0.x + v0.y + v0.z + v0.w + v1.x + v1.y + v1.z + v1.w;
    float sq = v0.x * v0.x + v0.y * v0.y + v0.z * v0.z + v0.w * v0.w +
               v1.x * v1.x + v1.y * v1.y + v1.z * v1.z + v1.w * v1.w;
#pragma unroll
    for (int msk = 1; msk < 64; msk <<= 1) {
        s += __shfl_xor(s, msk);
        sq += __shfl_xor(sq, msk);
    }
    float mu = s * (1.f / 512.f);
    float var = sq * (1.f / 512.f) - mu * mu;
    float rstd = rsqrtf(var + 1e-5f);
    float4 ga = *(const float4*)(g + lane * 8);
    float4 gb = *(const float4*)(g + lane * 8 + 4);
    float4 ba = *(const float4*)(b + lane * 8);
    float4 bb = *(const float4*)(b + lane * 8 + 4);
    float o0 = (v0.x - mu) * rstd * ga.x + ba.x;
    float o1 = (v0.y - mu) * rstd * ga.y + ba.y;
    float o2 = (v0.z - mu) * rstd * ga.z + ba.z;
    float o3 = (v0.w - mu) * rstd * ga.w + ba.w;
    float o4 = (v1.x - mu) * rstd * gb.x + bb.x;
    float o5 = (v1.y - mu) * rstd * gb.y + bb.y;
    float o6 = (v1.z - mu) * rstd * gb.z + bb.z;
    float o7 = (v1.w - mu) * rstd * gb.w + bb.w;
    float* orow = outf + (size_t)row * 512 + lane * 8;
    *(float4*)(orow) = make_float4(o0, o1, o2, o3);
    *(float4*)(orow + 4) = make_float4(o4, o5, o6, o7);
    if (outh) {
        h8 oh = {(_Float16)o0, (_Float16)o1, (_Float16)o2, (_Float16)o3,
                 (_Float16)o4, (_Float16)o5, (_Float16)o6, (_Float16)o7};
        *(h8*)(outh + (size_t)row * 512 + lane * 8) = oh;
    }
    if (tail && blockIdx.x == 0 && threadIdx.x == 0) tail[0] = 0.f;
}

// ---------------- launch ----------------
extern "C" void kernel_launch(void* const* d_in, const int* in_sizes, int n_in,
                              void* d_out, int out_size, void* d_ws, size_t ws_size,
                              hipStream_t stream) {
    const float* x   = (const float*)d_in[0];
    const float* Wq  = (const float*)d_in[1];
    const float* Wk  = (const float*)d_in[2];
    const float* Wv  = (const float*)d_in[3];
    const float* Wo  = (const float*)d_in[4];
    const float* bo  = (const float*)d_in[5];
    const float* g1  = (const float*)d_in[6];
    const float* b1  = (const float*)d_in[7];
    const float* W1  = (const float*)d_in[8];
    const float* bf1 = (const float*)d_in[9];
    const float* W2  = (const float*)d_in[10];
    const float* bf2 = (const float*)d_in[11];
    const float* g2  = (const float*)d_in[12];
    const float* b2  = (const float*)d_in[13];
    float* out = (float*)d_out;

    char* ws = (char*)d_ws;
    // byte offsets (all 256B-aligned); total ~78 MB
    _Float16* xh    = (_Float16*)(ws + 0);            // 8 MB; reused as out1h after QKV GEMM
    _Float16* wqkvT = (_Float16*)(ws + 8388608);      // 1.5 MB  [1536][512]
    _Float16* woT   = (_Float16*)(ws + 9961472);      // 0.5 MB
    _Float16* w1T   = (_Float16*)(ws + 10485760);     // 2 MB    [2048][512]
    _Float16* w2T   = (_Float16*)(ws + 12582912);     // 2 MB    [512][2048]
    _Float16* qb    = (_Float16*)(ws + 14680064);     // 8 MB; ff (32 MB) reuses qb..attnb
    _Float16* kb    = (_Float16*)(ws + 23068672);     // 8 MB
    _Float16* vtb   = (_Float16*)(ws + 31457280);     // 8 MB
    _Float16* attnb = (_Float16*)(ws + 39845888);     // 8 MB
    float*    h1    = (float*)(ws + 48234496);        // 16 MB fp32; reused as h2
    float*    out1f = (float*)(ws + 65011712);        // 16 MB fp32
    _Float16* out1h = xh;
    _Float16* ff    = qb;

    // stage 0: dtype conversion + fused weight transposes
    k_cvt<<<dim3(M_ * E_ / 1024), 256, 0, stream>>>(x, xh, M_ * E_);
    k_tr6<<<dim3(256, 1, 12), 256, 0, stream>>>(Wq, Wk, Wv, Wo, W1, W2,
                                                wqkvT, woT, w1T, w2T);

    // QKV projection (fused, N=1536): BN=128 -> grid 12*128 = 1536
    k_gemm<128, 0><<<dim3(1536), 256, 0, stream>>>(
        xh, wqkvT, M_, 1536, 512, nullptr, nullptr, nullptr, nullptr, qb, kb, vtb);

    // attention: 1024 blocks, XCD-decoded
    k_attn<<<dim3(1024), 256, 0, stream>>>(qb, kb, vtb, attnb);

    // Wo projection + bias + residual(x) -> h1 (fp32): BN=64 -> grid 8*128 = 1024
    k_gemm<64, 1><<<dim3(1024), 256, 0, stream>>>(
        attnb, woT, M_, 512, 512, bo, x, h1, nullptr, nullptr, nullptr, nullptr);

    // LN1 -> out1f (fp32) + out1h (f16)
    k_ln<<<dim3(M_ / 4), 256, 0, stream>>>(h1, g1, b1, out1f, out1h, nullptr);

    // FFN1: relu(out1 @ W1 + bf1) -> ff (f16): BN=128 -> grid 16*128 = 2048
    k_gemm<128, 2><<<dim3(2048), 256, 0, stream>>>(
        out1h, w1T, M_, 2048, 512, bf1, nullptr, nullptr, ff, nullptr, nullptr, nullptr);

    // FFN2: ff @ W2 + bf2 + out1 -> h1 (reused as h2, fp32): BN=64 -> grid 1024
    k_gemm<64, 1><<<dim3(1024), 256, 0, stream>>>(
        ff, w2T, M_, 512, 2048, bf2, out1f, h1, nullptr, nullptr, nullptr, nullptr);

    // LN2 -> d_out (fp32) + trailing scalar (reference returns (out3, 0))
    k_ln<<<dim3(M_ / 4), 256, 0, stream>>>(h1, g2, b2, out, nullptr, out + (size_t)M_ * E_);
}

// Round 8
// 152.158 us; speedup vs baseline: 1.8470x; 1.0672x over previous
//
#include <hip/hip_runtime.h>
#include <cstdint>
#include <cstddef>

// ---------------- types ----------------
typedef _Float16 h8 __attribute__((ext_vector_type(8)));
typedef _Float16 h4 __attribute__((ext_vector_type(4)));
typedef __fp16   g2 __attribute__((ext_vector_type(2)));   // cvt_pkrtz result type
typedef float    f32x4 __attribute__((ext_vector_type(4)));

constexpr int B_ = 8, N_ = 1024, E_ = 512, H_ = 8, D_ = 64, F_ = 2048;
constexpr int M_ = B_ * N_;   // 8192 rows
constexpr int HD_ = H_ * D_;  // 512

// q pre-scale: 1/sqrt(D) * log2(e)  (softmax done in base 2)
#define QSCALE2 0.18033688011112042f

#define GLOAD_LDS16(gp, lp)                                                        \
    __builtin_amdgcn_global_load_lds((const __attribute__((address_space(1))) void*)(gp), \
                                     (__attribute__((address_space(3))) void*)(lp), 16, 0, 0)

// ---------------- f32 -> f16 elementwise ----------------
__global__ void __launch_bounds__(256) k_cvt(const float* __restrict__ in,
                                             _Float16* __restrict__ out, int n) {
    int i = (blockIdx.x * 256 + threadIdx.x) * 4;
    if (i + 3 < n) {
        float4 v = *(const float4*)(in + i);
        h4 o = {(_Float16)v.x, (_Float16)v.y, (_Float16)v.z, (_Float16)v.w};
        *(h4*)(out + i) = o;
    }
}

// ---------------- fused 6-way weight transpose, LDS 32x32 tiles ----------------
__global__ void __launch_bounds__(256) k_tr6(
    const float* __restrict__ Wq, const float* __restrict__ Wk,
    const float* __restrict__ Wv, const float* __restrict__ Wo,
    const float* __restrict__ W1, const float* __restrict__ W2,
    _Float16* __restrict__ oqkv, _Float16* __restrict__ oo,
    _Float16* __restrict__ o1, _Float16* __restrict__ o2) {
    const float* in;
    _Float16* out;
    int R, C, gt = blockIdx.x;
    switch (blockIdx.z) {
        case 0: in = Wq; out = oqkv;              R = 512;  C = 512;  break;
        case 1: in = Wk; out = oqkv + 512 * 512;  R = 512;  C = 512;  break;
        case 2: in = Wv; out = oqkv + 1024 * 512; R = 512;  C = 512;  break;
        case 3: in = Wo; out = oo;                R = 512;  C = 512;  break;
        default:
            if (blockIdx.z < 8) { in = W1; out = o1; R = 512;  C = 2048; gt += (blockIdx.z - 4) * 256; }
            else                { in = W2; out = o2; R = 2048; C = 512;  gt += (blockIdx.z - 8) * 256; }
    }
    const int ctiles = C >> 5;
    const int ty = gt / ctiles, tx = gt - ty * ctiles;
    const int r0 = ty * 32, c0 = tx * 32;
    __shared__ float lt[32][33];
    const int rr = threadIdx.x >> 3, cq = threadIdx.x & 7;
    float4 v = *(const float4*)&in[(size_t)(r0 + rr) * C + c0 + cq * 4];
    lt[rr][cq * 4 + 0] = v.x; lt[rr][cq * 4 + 1] = v.y;
    lt[rr][cq * 4 + 2] = v.z; lt[rr][cq * 4 + 3] = v.w;
    __syncthreads();
    h4 o = {(_Float16)lt[cq * 4 + 0][rr], (_Float16)lt[cq * 4 + 1][rr],
            (_Float16)lt[cq * 4 + 2][rr], (_Float16)lt[cq * 4 + 3][rr]};
    *(h4*)&out[(size_t)(c0 + rr) * R + r0 + cq * 4] = o;
}

// ---------------- GEMM: C = A[M][K] * Bt[N][K]^T, f16 in, fp32 acc ----------------
// BM=64 fixed; BN templated. XCD-aware 1-D grid decode (T1), XOR-swizzled LDS (T2),
// 2-phase double-buffered prefetch (T3-min).
// EPI 0: QKV scatter (q *= QSCALE2, k direct, v transposed via LDS)
// EPI 1: outh = f16(acc + bias[col] + res_f32[row][col])   (Wo + x residual)
// EPI 2: outh = relu(acc + bias[col])                      (f16)
// EPI 3: outh = f16(acc + bias[col] + resh_f16[row][col])  (FFN2 + out1 residual)
template <int BN, int EPI>
__global__ void __launch_bounds__(256) k_gemm(
    const _Float16* __restrict__ A, const _Float16* __restrict__ Bt,
    int Mg, int Ng, int Kg,
    const float* __restrict__ bias, const float* __restrict__ res,
    const _Float16* __restrict__ resh, _Float16* __restrict__ outh,
    _Float16* __restrict__ qp, _Float16* __restrict__ kp, _Float16* __restrict__ vtp) {
    constexpr int WN = BN / 2;       // wave tile cols
    constexpr int NI = WN / 16;      // n-frags per wave
    __shared__ alignas(16) _Float16 lA[2][64 * 64];
    __shared__ alignas(16) _Float16 lB[2][BN * 64];

    const int tid = threadIdx.x;
    const int lane = tid & 63;
    const int wid = tid >> 6;
    const int wr = wid >> 1, wc = wid & 1;
    const int r16 = lane & 15, hseg = lane >> 4;

    // XCD-aware tile decode (M tiles = 128 always: 16 per XCD)
    const int bid = blockIdx.x;
    const int xcd = bid & 7;
    const int rem = bid >> 3;
    const int tx = rem >> 4, tyl = rem & 15;
    const int m0 = (xcd * 16 + tyl) * 64;
    const int n0 = tx * BN;

    auto STAGE = [&](int buf, int k0) {
#pragma unroll
        for (int i = 0; i < 2; ++i) {
            const int slot = i * 256 + tid, row = slot >> 3;
            const int cs = (slot & 7) ^ (row & 7);
            GLOAD_LDS16(A + (size_t)(m0 + row) * Kg + k0 + cs * 8, &lA[buf][slot * 8]);
        }
#pragma unroll
        for (int i = 0; i < BN / 32; ++i) {
            const int slot = i * 256 + tid, row = slot >> 3;
            const int cs = (slot & 7) ^ (row & 7);
            GLOAD_LDS16(Bt + (size_t)(n0 + row) * Kg + k0 + cs * 8, &lB[buf][slot * 8]);
        }
    };

    f32x4 acc[2][NI] = {};
    const int nt = Kg >> 6;

    STAGE(0, 0);
    __syncthreads();  // vmcnt(0)+barrier: buf0 ready

    for (int t = 0; t < nt; ++t) {
        const int cur = t & 1;
        if (t + 1 < nt) STAGE(cur ^ 1, (t + 1) << 6);  // prefetch overlaps compute

#pragma unroll
        for (int kk = 0; kk < 2; ++kk) {
            h8 af[2], bf[NI];
#pragma unroll
            for (int mi = 0; mi < 2; ++mi) {
                const int row = wr * 32 + mi * 16 + r16;
                af[mi] = *(const h8*)&lA[cur][row * 64 + (((kk * 4 + hseg) ^ (row & 7)) * 8)];
            }
#pragma unroll
            for (int ni = 0; ni < NI; ++ni) {
                const int row = wc * WN + ni * 16 + r16;
                bf[ni] = *(const h8*)&lB[cur][row * 64 + (((kk * 4 + hseg) ^ (row & 7)) * 8)];
            }
#pragma unroll
            for (int mi = 0; mi < 2; ++mi)
#pragma unroll
                for (int ni = 0; ni < NI; ++ni)
                    acc[mi][ni] =
                        __builtin_amdgcn_mfma_f32_16x16x32_f16(af[mi], bf[ni], acc[mi][ni], 0, 0, 0);
        }
        __syncthreads();  // drains prefetch vmcnt + read lgkmcnt, guards buffer swap
    }

    // epilogue: lane holds C[row = m0+wr*32+mi*16+hseg*4+r][col = n0+wc*WN+ni*16+r16]
    if constexpr (EPI == 0) {
        if (n0 >= 1024) {
            // V block: transpose 64xBN C-tile through LDS, coalesced h8 stores.
            _Float16* lC = &lA[0][0];
#pragma unroll
            for (int mi = 0; mi < 2; ++mi) {
                const int r0 = wr * 32 + mi * 16 + hseg * 4;
                const int s = r0 >> 3, ro = r0 & 7;
#pragma unroll
                for (int ni = 0; ni < NI; ++ni) {
                    const int c = wc * WN + ni * 16 + r16;
                    h4 pv = {(_Float16)acc[mi][ni][0], (_Float16)acc[mi][ni][1],
                             (_Float16)acc[mi][ni][2], (_Float16)acc[mi][ni][3]};
                    *(h4*)&lC[c * 64 + ((s ^ (c & 7)) << 3) + ro] = pv;
                }
            }
            __syncthreads();
            const int c = tid >> 1, half = tid & 1;
            const int b = m0 >> 10, nn0 = m0 & 1023;
            _Float16* gdst =
                vtp + ((size_t)(b * 512 + (n0 - 1024) + c)) * 1024 + nn0 + half * 32;
#pragma unroll
            for (int j = 0; j < 4; ++j) {
                const int s = half * 4 + j;
                h8 v = *(const h8*)&lC[c * 64 + ((s ^ (c & 7)) << 3)];
                *(h8*)&gdst[j * 8] = v;
            }
        } else {
#pragma unroll
            for (int mi = 0; mi < 2; ++mi)
#pragma unroll
                for (int ni = 0; ni < NI; ++ni)
#pragma unroll
                    for (int r = 0; r < 4; ++r) {
                        int row = m0 + wr * 32 + mi * 16 + hseg * 4 + r;
                        int col = n0 + wc * WN + ni * 16 + r16;
                        float v = acc[mi][ni][r];
                        int cc = col & 511;
                        int h = cc >> 6, d = cc & 63;
                        int b = row >> 10, nn = row & 1023;
                        if (col < 512)
                            qp[((b * 8 + h) * 1024 + nn) * 64 + d] = (_Float16)(v * QSCALE2);
                        else
                            kp[((b * 8 + h) * 1024 + nn) * 64 + d] = (_Float16)v;
                    }
        }
    } else {
#pragma unroll
        for (int mi = 0; mi < 2; ++mi)
#pragma unroll
            for (int ni = 0; ni < NI; ++ni)
#pragma unroll
                for (int r = 0; r < 4; ++r) {
                    int row = m0 + wr * 32 + mi * 16 + hseg * 4 + r;
                    int col = n0 + wc * WN + ni * 16 + r16;
                    float v = acc[mi][ni][r] + bias[col];
                    if constexpr (EPI == 1) {
                        v += res[(size_t)row * Ng + col];
                    } else if constexpr (EPI == 3) {
                        v += (float)resh[(size_t)row * Ng + col];
                    } else {
                        v = v > 0.f ? v : 0.f;
                    }
                    outh[(size_t)row * Ng + col] = (_Float16)v;
                }
    }
}

// ---------------- flash attention: 1 block = (b,h) x 64 q-rows ----------------
// Swapped QK^T (T12 mechanism) + XOR-swizzled LDS + 2-phase prefetch with
// LITERAL buffer indices (unrolled pairs) + hoisted per-lane LDS byte offsets.
// One lK/lV buffer = 64*64 f16 = 8192 BYTES (cOff = cur * 8192 — R7 bug was 16384).
__global__ void __launch_bounds__(256) k_attn(const _Float16* __restrict__ q,
                                              const _Float16* __restrict__ k,
                                              const _Float16* __restrict__ vt,
                                              _Float16* __restrict__ attn) {
    __shared__ alignas(16) _Float16 lK[2][64 * 64];   // [key][d], swizzled
    __shared__ alignas(16) _Float16 lV[2][64 * 64];   // [d][key], swizzled
    __shared__ alignas(16) _Float16 lP[4][16 * 64];   // per-wave P tile, swizzled

    const int tid = threadIdx.x, lane = tid & 63, w = tid >> 6;
    const int bid = blockIdx.x;
    const int xcd = bid & 7, rem = bid >> 3;
    const int bh = xcd * 8 + (rem & 7);
    const int q0 = (rem >> 3) * 64;
    const int r16 = lane & 15, hseg = lane >> 4;
    const size_t base = (size_t)bh * N_ * D_;

    // Q fragments (pre-scaled by QSCALE2 at QKV epilogue), held all kernel
    h8 qf0 = *(const h8*)&q[base + (size_t)(q0 + w * 16 + r16) * 64 + hseg * 8];
    h8 qf1 = *(const h8*)&q[base + (size_t)(q0 + w * 16 + r16) * 64 + 32 + hseg * 8];

    // per-lane swizzled staging source: slot -> (row, c ^ (row&7))
    int srow[2], scsrc[2];
#pragma unroll
    for (int i = 0; i < 2; ++i) {
        int slot = i * 256 + tid;
        srow[i] = slot >> 3;
        scsrc[i] = (slot & 7) ^ (srow[i] & 7);
    }

    auto STAGE = [&](int buf, int kt) {
#pragma unroll
        for (int i = 0; i < 2; ++i)
            GLOAD_LDS16(k + base + kt * 4096 + srow[i] * 64 + scsrc[i] * 8,
                        &lK[buf][(i * 256 + tid) * 8]);
#pragma unroll
        for (int i = 0; i < 2; ++i)
            GLOAD_LDS16(vt + base + (size_t)srow[i] * N_ + kt * 64 + scsrc[i] * 8,
                        &lV[buf][(i * 256 + tid) * 8]);
    };

    // softmax state for q-row (q0 + w*16 + r16): lane-local scalars
    float mrun = -1e30f, lrun = 0.f;
    f32x4 oacc[4] = {};  // O[q = hseg*4+r][d = nf*16+r16]

    // hoisted per-lane LDS byte offsets (kt-invariant)
    const char* lKb = (const char*)&lK[0][0];
    const char* lVb = (const char*)&lV[0][0];
    char* lPb = (char*)&lP[0][0] + w * 2048;
    const int swz = r16 & 7;
    const int kb0 = r16 * 128 + ((hseg ^ swz) * 16);        // kc=0 (lK & lV share)
    const int kb1 = r16 * 128 + (((4 + hseg) ^ swz) * 16);  // kc=1
    const int pswz = swz * 8;
    const int prd0 = r16 * 128 + (((hseg * 8) ^ pswz) * 2);
    const int prd1 = r16 * 128 + (((32 + hseg * 8) ^ pswz) * 2);
    const int pwr0 = r16 * 128 + (((0 + hseg * 4) ^ pswz) * 2);
    const int pwr1 = r16 * 128 + (((16 + hseg * 4) ^ pswz) * 2);
    const int pwr2 = r16 * 128 + (((32 + hseg * 4) ^ pswz) * 2);
    const int pwr3 = r16 * 128 + (((48 + hseg * 4) ^ pswz) * 2);

    auto TILE = [&](const int cur, const int kt) __attribute__((always_inline)) {
        if (kt + 1 < N_ / 64) STAGE(cur ^ 1, kt + 1);  // prefetch overlaps compute
        const int cOff = cur * 8192;  // one buffer = 64*64*2 bytes

        // S tiles swapped: sv[t4][r] = S[key = t4*16 + hseg*4 + r][q = r16]
        float sv[4][4];
#pragma unroll
        for (int t4 = 0; t4 < 4; ++t4) {
            f32x4 a = {};
            h8 kf0 = *(const h8*)(lKb + cOff + t4 * 2048 + kb0);
            a = __builtin_amdgcn_mfma_f32_16x16x32_f16(kf0, qf0, a, 0, 0, 0);
            h8 kf1 = *(const h8*)(lKb + cOff + t4 * 2048 + kb1);
            a = __builtin_amdgcn_mfma_f32_16x16x32_f16(kf1, qf1, a, 0, 0, 0);
#pragma unroll
            for (int r = 0; r < 4; ++r) sv[t4][r] = a[r];
        }

        // in-lane max over 16 values + 2 cross-lane steps
        float mx = sv[0][0];
#pragma unroll
        for (int t4 = 0; t4 < 4; ++t4)
#pragma unroll
            for (int r = 0; r < 4; ++r) mx = fmaxf(mx, sv[t4][r]);
        mx = fmaxf(mx, __shfl_xor(mx, 16));
        mx = fmaxf(mx, __shfl_xor(mx, 32));

        // defer-max (T13, THR=8 in log2 units -> P <= 256, f16-safe)
        if (__any(mx > mrun + 8.f)) {
            float mnew = fmaxf(mrun, mx);
            float sc = exp2f(mrun - mnew);
            mrun = mnew;
            lrun *= sc;
#pragma unroll
            for (int r = 0; r < 4; ++r) {
                float scq = __shfl(sc, hseg * 4 + r);
#pragma unroll
                for (int nf = 0; nf < 4; ++nf) oacc[nf][r] *= scq;
            }
        }

        // P = exp2(S - m), in-lane sum + 2 cross-lane steps
        float p[4][4];
        float rsum = 0.f;
#pragma unroll
        for (int t4 = 0; t4 < 4; ++t4)
#pragma unroll
            for (int r = 0; r < 4; ++r) {
                p[t4][r] = exp2f(sv[t4][r] - mrun);
                rsum += p[t4][r];
            }
        rsum += __shfl_xor(rsum, 16);
        rsum += __shfl_xor(rsum, 32);
        lrun += rsum;

        // P -> A-operand layout via per-wave LDS (packed converts, b64 writes)
#pragma unroll
        for (int t4 = 0; t4 < 4; ++t4) {
            g2 a0 = __builtin_amdgcn_cvt_pkrtz(p[t4][0], p[t4][1]);
            g2 a1 = __builtin_amdgcn_cvt_pkrtz(p[t4][2], p[t4][3]);
            h4 pv = {(_Float16)a0[0], (_Float16)a0[1], (_Float16)a1[0], (_Float16)a1[1]};
            char* dst = lPb + (t4 == 0 ? pwr0 : t4 == 1 ? pwr1 : t4 == 2 ? pwr2 : pwr3);
            *(h4*)dst = pv;
        }
        asm volatile("s_waitcnt lgkmcnt(0)" ::: "memory");  // wave-internal LDS fence

        h8 pa0 = *(const h8*)(lPb + prd0);
        h8 pa1 = *(const h8*)(lPb + prd1);
#pragma unroll
        for (int nf = 0; nf < 4; ++nf) {
            h8 vb0 = *(const h8*)(lVb + cOff + nf * 2048 + kb0);
            oacc[nf] = __builtin_amdgcn_mfma_f32_16x16x32_f16(pa0, vb0, oacc[nf], 0, 0, 0);
            h8 vb1 = *(const h8*)(lVb + cOff + nf * 2048 + kb1);
            oacc[nf] = __builtin_amdgcn_mfma_f32_16x16x32_f16(pa1, vb1, oacc[nf], 0, 0, 0);
        }
        __syncthreads();  // drains prefetch vmcnt + guards buffer swap
    };

    STAGE(0, 0);
    __syncthreads();  // drains vmcnt: buf0 ready

    for (int kt = 0; kt < N_ / 64; kt += 2) {
        TILE(0, kt);
        TILE(1, kt + 1);
    }

    // write attn_out [M][HD] f16; 1/l broadcast to C-row layout
    float rlin = 1.f / lrun;
    int b = bh >> 3, h = bh & 7;
#pragma unroll
    for (int r = 0; r < 4; ++r) {
        float inv = __shfl(rlin, hseg * 4 + r);
        int row = b * 1024 + q0 + w * 16 + hseg * 4 + r;
#pragma unroll
        for (int nf = 0; nf < 4; ++nf) {
            int col = h * 64 + nf * 16 + r16;
            attn[(size_t)row * 512 + col] = (_Float16)(oacc[nf][r] * inv);
        }
    }
}

// ---------------- layernorm: 1 wave per row of 512, f16 in ----------------
// OUTF32=1: write f32 (+tail); else write f16.
template <int OUTF32>
__global__ void __launch_bounds__(256) k_ln(const _Float16* __restrict__ x,
                                            const float* __restrict__ g,
                                            const float* __restrict__ b,
                                            float* __restrict__ outf,
                                            _Float16* __restrict__ outh,
                                            float* __restrict__ tail) {
    int row = blockIdx.x * 4 + (threadIdx.x >> 6);
    int lane = threadIdx.x & 63;
    h8 v = *(const h8*)(x + (size_t)row * 512 + lane * 8);
    float f[8];
    float s = 0.f, sq = 0.f;
#pragma unroll
    for (int j = 0; j < 8; ++j) {
        f[j] = (float)v[j];
        s += f[j];
        sq += f[j] * f[j];
    }
#pragma unroll
    for (int msk = 1; msk < 64; msk <<= 1) {
        s += __shfl_xor(s, msk);
        sq += __shfl_xor(sq, msk);
    }
    float mu = s * (1.f / 512.f);
    float var = sq * (1.f / 512.f) - mu * mu;
    float rstd = rsqrtf(var + 1e-5f);
    float4 ga = *(const float4*)(g + lane * 8);
    float4 gb = *(const float4*)(g + lane * 8 + 4);
    float4 ba = *(const float4*)(b + lane * 8);
    float4 bb = *(const float4*)(b + lane * 8 + 4);
    float o[8];
    o[0] = (f[0] - mu) * rstd * ga.x + ba.x;
    o[1] = (f[1] - mu) * rstd * ga.y + ba.y;
    o[2] = (f[2] - mu) * rstd * ga.z + ba.z;
    o[3] = (f[3] - mu) * rstd * ga.w + ba.w;
    o[4] = (f[4] - mu) * rstd * gb.x + bb.x;
    o[5] = (f[5] - mu) * rstd * gb.y + bb.y;
    o[6] = (f[6] - mu) * rstd * gb.z + bb.z;
    o[7] = (f[7] - mu) * rstd * gb.w + bb.w;
    if constexpr (OUTF32) {
        float* orow = outf + (size_t)row * 512 + lane * 8;
        *(float4*)(orow) = make_float4(o[0], o[1], o[2], o[3]);
        *(float4*)(orow + 4) = make_float4(o[4], o[5], o[6], o[7]);
        if (tail && blockIdx.x == 0 && threadIdx.x == 0) tail[0] = 0.f;
    } else {
        h8 oh = {(_Float16)o[0], (_Float16)o[1], (_Float16)o[2], (_Float16)o[3],
                 (_Float16)o[4], (_Float16)o[5], (_Float16)o[6], (_Float16)o[7]};
        *(h8*)(outh + (size_t)row * 512 + lane * 8) = oh;
    }
}

// ---------------- launch ----------------
extern "C" void kernel_launch(void* const* d_in, const int* in_sizes, int n_in,
                              void* d_out, int out_size, void* d_ws, size_t ws_size,
                              hipStream_t stream) {
    const float* x   = (const float*)d_in[0];
    const float* Wq  = (const float*)d_in[1];
    const float* Wk  = (const float*)d_in[2];
    const float* Wv  = (const float*)d_in[3];
    const float* Wo  = (const float*)d_in[4];
    const float* bo  = (const float*)d_in[5];
    const float* g1  = (const float*)d_in[6];
    const float* b1  = (const float*)d_in[7];
    const float* W1  = (const float*)d_in[8];
    const float* bf1 = (const float*)d_in[9];
    const float* W2  = (const float*)d_in[10];
    const float* bf2 = (const float*)d_in[11];
    const float* g2  = (const float*)d_in[12];
    const float* b2  = (const float*)d_in[13];
    float* out = (float*)d_out;

    char* ws = (char*)d_ws;
    _Float16* xh    = (_Float16*)(ws + 0);            // 8 MB; reused as out1h after QKV GEMM
    _Float16* wqkvT = (_Float16*)(ws + 8388608);      // 1.5 MB  [1536][512]
    _Float16* woT   = (_Float16*)(ws + 9961472);      // 0.5 MB
    _Float16* w1T   = (_Float16*)(ws + 10485760);     // 2 MB    [2048][512]
    _Float16* w2T   = (_Float16*)(ws + 12582912);     // 2 MB    [512][2048]
    _Float16* qb    = (_Float16*)(ws + 14680064);     // 8 MB; ff (32 MB) reuses qb..attnb
    _Float16* kb    = (_Float16*)(ws + 23068672);     // 8 MB
    _Float16* vtb   = (_Float16*)(ws + 31457280);     // 8 MB
    _Float16* attnb = (_Float16*)(ws + 39845888);     // 8 MB
    _Float16* h1h   = (_Float16*)(ws + 48234496);     // 8 MB f16 (h1, reused as h2)
    _Float16* out1h = xh;
    _Float16* ff    = qb;

    // stage 0: dtype conversion + fused weight transposes
    k_cvt<<<dim3(M_ * E_ / 1024), 256, 0, stream>>>(x, xh, M_ * E_);
    k_tr6<<<dim3(256, 1, 12), 256, 0, stream>>>(Wq, Wk, Wv, Wo, W1, W2,
                                                wqkvT, woT, w1T, w2T);

    // QKV projection (fused, N=1536): BN=128 -> grid 12*128 = 1536
    k_gemm<128, 0><<<dim3(1536), 256, 0, stream>>>(
        xh, wqkvT, M_, 1536, 512, nullptr, nullptr, nullptr, nullptr, qb, kb, vtb);

    // attention: 1024 blocks, XCD-decoded
    k_attn<<<dim3(1024), 256, 0, stream>>>(qb, kb, vtb, attnb);

    // Wo projection + bias + residual(x, f32) -> h1h (f16): BN=64 -> grid 1024
    k_gemm<64, 1><<<dim3(1024), 256, 0, stream>>>(
        attnb, woT, M_, 512, 512, bo, x, nullptr, h1h, nullptr, nullptr, nullptr);

    // LN1 -> out1h (f16)
    k_ln<0><<<dim3(M_ / 4), 256, 0, stream>>>(h1h, g1, b1, nullptr, out1h, nullptr);

    // FFN1: relu(out1 @ W1 + bf1) -> ff (f16): BN=128 -> grid 2048
    k_gemm<128, 2><<<dim3(2048), 256, 0, stream>>>(
        out1h, w1T, M_, 2048, 512, bf1, nullptr, nullptr, ff, nullptr, nullptr, nullptr);

    // FFN2: ff @ W2 + bf2 + out1 (f16 residual) -> h1h reused (f16): BN=64
    k_gemm<64, 3><<<dim3(1024), 256, 0, stream>>>(
        ff, w2T, M_, 512, 2048, bf2, nullptr, out1h, h1h, nullptr, nullptr, nullptr);

    // LN2 -> d_out (fp32) + trailing scalar (reference returns (out3, 0))
    k_ln<1><<<dim3(M_ / 4), 256, 0, stream>>>(h1h, g2, b2, out, nullptr, out + (size_t)M_ * E_);
}

// Round 9
// 143.473 us; speedup vs baseline: 1.9588x; 1.0605x over previous
//
#include <hip/hip_runtime.h>
#include <cstdint>
#include <cstddef>

// ---------------- types ----------------
typedef _Float16 h8 __attribute__((ext_vector_type(8)));
typedef _Float16 h4 __attribute__((ext_vector_type(4)));
typedef __fp16   g2 __attribute__((ext_vector_type(2)));   // cvt_pkrtz result type
typedef float    f32x4 __attribute__((ext_vector_type(4)));

constexpr int B_ = 8, N_ = 1024, E_ = 512, H_ = 8, D_ = 64, F_ = 2048;
constexpr int M_ = B_ * N_;   // 8192 rows
constexpr int HD_ = H_ * D_;  // 512

// q pre-scale: 1/sqrt(D) * log2(e)  (softmax done in base 2)
#define QSCALE2 0.18033688011112042f

#define GLOAD_LDS16(gp, lp)                                                        \
    __builtin_amdgcn_global_load_lds((const __attribute__((address_space(1))) void*)(gp), \
                                     (__attribute__((address_space(3))) void*)(lp), 16, 0, 0)

// raw hardware exp2 (no libm denormal guard; underflow -> 0 is fine for softmax)
__device__ __forceinline__ float exp2_raw(float x) {
#if __has_builtin(__builtin_amdgcn_exp2f)
    return __builtin_amdgcn_exp2f(x);
#else
    float r;
    asm("v_exp_f32 %0, %1\n\ts_nop 0" : "=v"(r) : "v"(x));
    return r;
#endif
}

// ---------------- fused prep: weight transposes (z<12) + x f32->f16 (z==12) ----
__global__ void __launch_bounds__(256) k_pre(
    const float* __restrict__ x, _Float16* __restrict__ xh,
    const float* __restrict__ Wq, const float* __restrict__ Wk,
    const float* __restrict__ Wv, const float* __restrict__ Wo,
    const float* __restrict__ W1, const float* __restrict__ W2,
    _Float16* __restrict__ oqkv, _Float16* __restrict__ oo,
    _Float16* __restrict__ o1, _Float16* __restrict__ o2) {
    if (blockIdx.z == 12) {
        // cvt: 1024 x-blocks * 256 threads * 16 elems = 4,194,304 = M_*E_
        int i = (blockIdx.x * 256 + threadIdx.x) * 16;
#pragma unroll
        for (int j = 0; j < 4; ++j) {
            float4 v = *(const float4*)(x + i + j * 4);
            h4 o = {(_Float16)v.x, (_Float16)v.y, (_Float16)v.z, (_Float16)v.w};
            *(h4*)(xh + i + j * 4) = o;
        }
        return;
    }
    if (blockIdx.x >= 256) return;
    const float* in;
    _Float16* out;
    int R, C, gt = blockIdx.x;
    switch (blockIdx.z) {
        case 0: in = Wq; out = oqkv;              R = 512;  C = 512;  break;
        case 1: in = Wk; out = oqkv + 512 * 512;  R = 512;  C = 512;  break;
        case 2: in = Wv; out = oqkv + 1024 * 512; R = 512;  C = 512;  break;
        case 3: in = Wo; out = oo;                R = 512;  C = 512;  break;
        default:
            if (blockIdx.z < 8) { in = W1; out = o1; R = 512;  C = 2048; gt += (blockIdx.z - 4) * 256; }
            else                { in = W2; out = o2; R = 2048; C = 512;  gt += (blockIdx.z - 8) * 256; }
    }
    const int ctiles = C >> 5;
    const int ty = gt / ctiles, tx = gt - ty * ctiles;
    const int r0 = ty * 32, c0 = tx * 32;
    __shared__ float lt[32][33];
    const int rr = threadIdx.x >> 3, cq = threadIdx.x & 7;
    float4 v = *(const float4*)&in[(size_t)(r0 + rr) * C + c0 + cq * 4];
    lt[rr][cq * 4 + 0] = v.x; lt[rr][cq * 4 + 1] = v.y;
    lt[rr][cq * 4 + 2] = v.z; lt[rr][cq * 4 + 3] = v.w;
    __syncthreads();
    h4 o = {(_Float16)lt[cq * 4 + 0][rr], (_Float16)lt[cq * 4 + 1][rr],
            (_Float16)lt[cq * 4 + 2][rr], (_Float16)lt[cq * 4 + 3][rr]};
    *(h4*)&out[(size_t)(c0 + rr) * R + r0 + cq * 4] = o;
}

// ---------------- GEMM: C = A[M][K] * Bt[N][K]^T, f16 in, fp32 acc ----------------
// BM=64 fixed; BN templated. XCD-aware 1-D grid decode (T1), XOR-swizzled LDS (T2),
// 2-phase double-buffered prefetch (T3-min).
// EPI 0: QKV scatter (q *= QSCALE2, k direct, v transposed via LDS)
// EPI 1: outh = f16(acc + bias[col] + res_f32[row][col])   (Wo + x residual)
// EPI 2: outh = relu(acc + bias[col])                      (f16)
// EPI 3: outh = f16(acc + bias[col] + resh_f16[row][col])  (FFN2 + out1 residual)
template <int BN, int EPI>
__global__ void __launch_bounds__(256) k_gemm(
    const _Float16* __restrict__ A, const _Float16* __restrict__ Bt,
    int Mg, int Ng, int Kg,
    const float* __restrict__ bias, const float* __restrict__ res,
    const _Float16* __restrict__ resh, _Float16* __restrict__ outh,
    _Float16* __restrict__ qp, _Float16* __restrict__ kp, _Float16* __restrict__ vtp) {
    constexpr int WN = BN / 2;       // wave tile cols
    constexpr int NI = WN / 16;      // n-frags per wave
    __shared__ alignas(16) _Float16 lA[2][64 * 64];
    __shared__ alignas(16) _Float16 lB[2][BN * 64];

    const int tid = threadIdx.x;
    const int lane = tid & 63;
    const int wid = tid >> 6;
    const int wr = wid >> 1, wc = wid & 1;
    const int r16 = lane & 15, hseg = lane >> 4;

    // XCD-aware tile decode (M tiles = 128 always: 16 per XCD)
    const int bid = blockIdx.x;
    const int xcd = bid & 7;
    const int rem = bid >> 3;
    const int tx = rem >> 4, tyl = rem & 15;
    const int m0 = (xcd * 16 + tyl) * 64;
    const int n0 = tx * BN;

    auto STAGE = [&](int buf, int k0) {
#pragma unroll
        for (int i = 0; i < 2; ++i) {
            const int slot = i * 256 + tid, row = slot >> 3;
            const int cs = (slot & 7) ^ (row & 7);
            GLOAD_LDS16(A + (size_t)(m0 + row) * Kg + k0 + cs * 8, &lA[buf][slot * 8]);
        }
#pragma unroll
        for (int i = 0; i < BN / 32; ++i) {
            const int slot = i * 256 + tid, row = slot >> 3;
            const int cs = (slot & 7) ^ (row & 7);
            GLOAD_LDS16(Bt + (size_t)(n0 + row) * Kg + k0 + cs * 8, &lB[buf][slot * 8]);
        }
    };

    f32x4 acc[2][NI] = {};
    const int nt = Kg >> 6;

    STAGE(0, 0);
    __syncthreads();  // vmcnt(0)+barrier: buf0 ready

    for (int t = 0; t < nt; ++t) {
        const int cur = t & 1;
        if (t + 1 < nt) STAGE(cur ^ 1, (t + 1) << 6);  // prefetch overlaps compute

#pragma unroll
        for (int kk = 0; kk < 2; ++kk) {
            h8 af[2], bf[NI];
#pragma unroll
            for (int mi = 0; mi < 2; ++mi) {
                const int row = wr * 32 + mi * 16 + r16;
                af[mi] = *(const h8*)&lA[cur][row * 64 + (((kk * 4 + hseg) ^ (row & 7)) * 8)];
            }
#pragma unroll
            for (int ni = 0; ni < NI; ++ni) {
                const int row = wc * WN + ni * 16 + r16;
                bf[ni] = *(const h8*)&lB[cur][row * 64 + (((kk * 4 + hseg) ^ (row & 7)) * 8)];
            }
#pragma unroll
            for (int mi = 0; mi < 2; ++mi)
#pragma unroll
                for (int ni = 0; ni < NI; ++ni)
                    acc[mi][ni] =
                        __builtin_amdgcn_mfma_f32_16x16x32_f16(af[mi], bf[ni], acc[mi][ni], 0, 0, 0);
        }
        __syncthreads();  // drains prefetch vmcnt + read lgkmcnt, guards buffer swap
    }

    // epilogue: lane holds C[row = m0+wr*32+mi*16+hseg*4+r][col = n0+wc*WN+ni*16+r16]
    if constexpr (EPI == 0) {
        if (n0 >= 1024) {
            // V block: transpose 64xBN C-tile through LDS, coalesced h8 stores.
            _Float16* lC = &lA[0][0];
#pragma unroll
            for (int mi = 0; mi < 2; ++mi) {
                const int r0 = wr * 32 + mi * 16 + hseg * 4;
                const int s = r0 >> 3, ro = r0 & 7;
#pragma unroll
                for (int ni = 0; ni < NI; ++ni) {
                    const int c = wc * WN + ni * 16 + r16;
                    h4 pv = {(_Float16)acc[mi][ni][0], (_Float16)acc[mi][ni][1],
                             (_Float16)acc[mi][ni][2], (_Float16)acc[mi][ni][3]};
                    *(h4*)&lC[c * 64 + ((s ^ (c & 7)) << 3) + ro] = pv;
                }
            }
            __syncthreads();
            const int c = tid >> 1, half = tid & 1;
            const int b = m0 >> 10, nn0 = m0 & 1023;
            _Float16* gdst =
                vtp + ((size_t)(b * 512 + (n0 - 1024) + c)) * 1024 + nn0 + half * 32;
#pragma unroll
            for (int j = 0; j < 4; ++j) {
                const int s = half * 4 + j;
                h8 v = *(const h8*)&lC[c * 64 + ((s ^ (c & 7)) << 3)];
                *(h8*)&gdst[j * 8] = v;
            }
        } else {
#pragma unroll
            for (int mi = 0; mi < 2; ++mi)
#pragma unroll
                for (int ni = 0; ni < NI; ++ni)
#pragma unroll
                    for (int r = 0; r < 4; ++r) {
                        int row = m0 + wr * 32 + mi * 16 + hseg * 4 + r;
                        int col = n0 + wc * WN + ni * 16 + r16;
                        float v = acc[mi][ni][r];
                        int cc = col & 511;
                        int h = cc >> 6, d = cc & 63;
                        int b = row >> 10, nn = row & 1023;
                        if (col < 512)
                            qp[((b * 8 + h) * 1024 + nn) * 64 + d] = (_Float16)(v * QSCALE2);
                        else
                            kp[((b * 8 + h) * 1024 + nn) * 64 + d] = (_Float16)v;
                    }
        }
    } else {
#pragma unroll
        for (int mi = 0; mi < 2; ++mi)
#pragma unroll
            for (int ni = 0; ni < NI; ++ni)
#pragma unroll
                for (int r = 0; r < 4; ++r) {
                    int row = m0 + wr * 32 + mi * 16 + hseg * 4 + r;
                    int col = n0 + wc * WN + ni * 16 + r16;
                    float v = acc[mi][ni][r] + bias[col];
                    if constexpr (EPI == 1) {
                        v += res[(size_t)row * Ng + col];
                    } else if constexpr (EPI == 3) {
                        v += (float)resh[(size_t)row * Ng + col];
                    } else {
                        v = v > 0.f ? v : 0.f;
                    }
                    outh[(size_t)row * Ng + col] = (_Float16)v;
                }
    }
}

// ---------------- flash attention: 1 block = (b,h) x 64 q-rows ----------------
// Swapped QK^T (T12 mechanism) + XOR-swizzled LDS + 2-phase prefetch with literal
// buffer indices + hoisted per-lane LDS byte offsets. Steady-state tile has ZERO
// cross-lane ops: lrun kept as per-lane partial (reduced once at end); cross-lane
// max + rescale only when __any(in-lane max > mrun + 8) fires (rare after tile 0).
__global__ void __launch_bounds__(256) k_attn(const _Float16* __restrict__ q,
                                              const _Float16* __restrict__ k,
                                              const _Float16* __restrict__ vt,
                                              _Float16* __restrict__ attn) {
    __shared__ alignas(16) _Float16 lK[2][64 * 64];   // [key][d], swizzled
    __shared__ alignas(16) _Float16 lV[2][64 * 64];   // [d][key], swizzled
    __shared__ alignas(16) _Float16 lP[4][16 * 64];   // per-wave P tile, swizzled

    const int tid = threadIdx.x, lane = tid & 63, w = tid >> 6;
    const int bid = blockIdx.x;
    const int xcd = bid & 7, rem = bid >> 3;
    const int bh = xcd * 8 + (rem & 7);
    const int q0 = (rem >> 3) * 64;
    const int r16 = lane & 15, hseg = lane >> 4;
    const size_t base = (size_t)bh * N_ * D_;

    // Q fragments (pre-scaled by QSCALE2 at QKV epilogue), held all kernel
    h8 qf0 = *(const h8*)&q[base + (size_t)(q0 + w * 16 + r16) * 64 + hseg * 8];
    h8 qf1 = *(const h8*)&q[base + (size_t)(q0 + w * 16 + r16) * 64 + 32 + hseg * 8];

    // per-lane swizzled staging source: slot -> (row, c ^ (row&7))
    int srow[2], scsrc[2];
#pragma unroll
    for (int i = 0; i < 2; ++i) {
        int slot = i * 256 + tid;
        srow[i] = slot >> 3;
        scsrc[i] = (slot & 7) ^ (srow[i] & 7);
    }

    auto STAGE = [&](int buf, int kt) {
#pragma unroll
        for (int i = 0; i < 2; ++i)
            GLOAD_LDS16(k + base + kt * 4096 + srow[i] * 64 + scsrc[i] * 8,
                        &lK[buf][(i * 256 + tid) * 8]);
#pragma unroll
        for (int i = 0; i < 2; ++i)
            GLOAD_LDS16(vt + base + (size_t)srow[i] * N_ + kt * 64 + scsrc[i] * 8,
                        &lV[buf][(i * 256 + tid) * 8]);
    };

    // softmax state for q-row r16: mrun row-shared; lrun per-lane PARTIAL
    float mrun = -1e30f, lrun = 0.f;
    f32x4 oacc[4] = {};  // O[q = hseg*4+r][d = nf*16+r16]

    // hoisted per-lane LDS byte offsets (kt-invariant)
    const char* lKb = (const char*)&lK[0][0];
    const char* lVb = (const char*)&lV[0][0];
    char* lPb = (char*)&lP[0][0] + w * 2048;
    const int swz = r16 & 7;
    const int kb0 = r16 * 128 + ((hseg ^ swz) * 16);        // kc=0 (lK & lV share)
    const int kb1 = r16 * 128 + (((4 + hseg) ^ swz) * 16);  // kc=1
    const int pswz = swz * 8;
    const int prd0 = r16 * 128 + (((hseg * 8) ^ pswz) * 2);
    const int prd1 = r16 * 128 + (((32 + hseg * 8) ^ pswz) * 2);
    const int pwr0 = r16 * 128 + (((0 + hseg * 4) ^ pswz) * 2);
    const int pwr1 = r16 * 128 + (((16 + hseg * 4) ^ pswz) * 2);
    const int pwr2 = r16 * 128 + (((32 + hseg * 4) ^ pswz) * 2);
    const int pwr3 = r16 * 128 + (((48 + hseg * 4) ^ pswz) * 2);

    auto TILE = [&](const int cur, const int kt) __attribute__((always_inline)) {
        if (kt + 1 < N_ / 64) STAGE(cur ^ 1, kt + 1);  // prefetch overlaps compute
        const int cOff = cur * 8192;  // one buffer = 64*64*2 bytes

        // S tiles swapped: sv[t4][r] = S[key = t4*16 + hseg*4 + r][q = r16]
        float sv[4][4];
        __builtin_amdgcn_s_setprio(1);
#pragma unroll
        for (int t4 = 0; t4 < 4; ++t4) {
            f32x4 a = {};
            h8 kf0 = *(const h8*)(lKb + cOff + t4 * 2048 + kb0);
            a = __builtin_amdgcn_mfma_f32_16x16x32_f16(kf0, qf0, a, 0, 0, 0);
            h8 kf1 = *(const h8*)(lKb + cOff + t4 * 2048 + kb1);
            a = __builtin_amdgcn_mfma_f32_16x16x32_f16(kf1, qf1, a, 0, 0, 0);
#pragma unroll
            for (int r = 0; r < 4; ++r) sv[t4][r] = a[r];
        }
        __builtin_amdgcn_s_setprio(0);

        // in-lane max over this lane's 16 values (tree)
        float m0a = fmaxf(fmaxf(sv[0][0], sv[0][1]), fmaxf(sv[0][2], sv[0][3]));
        float m1a = fmaxf(fmaxf(sv[1][0], sv[1][1]), fmaxf(sv[1][2], sv[1][3]));
        float m2a = fmaxf(fmaxf(sv[2][0], sv[2][1]), fmaxf(sv[2][2], sv[2][3]));
        float m3a = fmaxf(fmaxf(sv[3][0], sv[3][1]), fmaxf(sv[3][2], sv[3][3]));
        float mx = fmaxf(fmaxf(m0a, m1a), fmaxf(m2a, m3a));

        // rescale only if some lane's local max breaches the threshold (rare)
        if (__any(mx > mrun + 8.f)) {
            mx = fmaxf(mx, __shfl_xor(mx, 16));
            mx = fmaxf(mx, __shfl_xor(mx, 32));
            float mnew = fmaxf(mrun, mx);
            float sc = exp2_raw(mrun - mnew);
            mrun = mnew;
            lrun *= sc;  // per-lane partial; sc row-uniform -> consistent
#pragma unroll
            for (int r = 0; r < 4; ++r) {
                float scq = __shfl(sc, hseg * 4 + r);
#pragma unroll
                for (int nf = 0; nf < 4; ++nf) oacc[nf][r] *= scq;
            }
        }

        // P = exp2(S - m); per-lane partial sum only (cross-lane deferred to end)
        float p[4][4];
        float rsum = 0.f;
#pragma unroll
        for (int t4 = 0; t4 < 4; ++t4)
#pragma unroll
            for (int r = 0; r < 4; ++r) {
                p[t4][r] = exp2_raw(sv[t4][r] - mrun);
                rsum += p[t4][r];
            }
        lrun += rsum;

        // P -> A-operand layout via per-wave LDS (packed converts, b64 writes)
#pragma unroll
        for (int t4 = 0; t4 < 4; ++t4) {
            g2 a0 = __builtin_amdgcn_cvt_pkrtz(p[t4][0], p[t4][1]);
            g2 a1 = __builtin_amdgcn_cvt_pkrtz(p[t4][2], p[t4][3]);
            h4 pv = {(_Float16)a0[0], (_Float16)a0[1], (_Float16)a1[0], (_Float16)a1[1]};
            char* dst = lPb + (t4 == 0 ? pwr0 : t4 == 1 ? pwr1 : t4 == 2 ? pwr2 : pwr3);
            *(h4*)dst = pv;
        }
        asm volatile("s_waitcnt lgkmcnt(0)" ::: "memory");  // wave-internal LDS fence

        h8 pa0 = *(const h8*)(lPb + prd0);
        h8 pa1 = *(const h8*)(lPb + prd1);
        __builtin_amdgcn_s_setprio(1);
#pragma unroll
        for (int nf = 0; nf < 4; ++nf) {
            h8 vb0 = *(const h8*)(lVb + cOff + nf * 2048 + kb0);
            oacc[nf] = __builtin_amdgcn_mfma_f32_16x16x32_f16(pa0, vb0, oacc[nf], 0, 0, 0);
            h8 vb1 = *(const h8*)(lVb + cOff + nf * 2048 + kb1);
            oacc[nf] = __builtin_amdgcn_mfma_f32_16x16x32_f16(pa1, vb1, oacc[nf], 0, 0, 0);
        }
        __builtin_amdgcn_s_setprio(0);
        __syncthreads();  // drains prefetch vmcnt + guards buffer swap
    };

    STAGE(0, 0);
    __syncthreads();  // drains vmcnt: buf0 ready

    for (int kt = 0; kt < N_ / 64; kt += 2) {
        TILE(0, kt);
        TILE(1, kt + 1);
    }

    // reduce the deferred partial sums (2 shuffles, once per kernel)
    lrun += __shfl_xor(lrun, 16);
    lrun += __shfl_xor(lrun, 32);

    // write attn_out [M][HD] f16; 1/l broadcast to C-row layout
    float rlin = 1.f / lrun;
    int b = bh >> 3, h = bh & 7;
#pragma unroll
    for (int r = 0; r < 4; ++r) {
        float inv = __shfl(rlin, hseg * 4 + r);
        int row = b * 1024 + q0 + w * 16 + hseg * 4 + r;
#pragma unroll
        for (int nf = 0; nf < 4; ++nf) {
            int col = h * 64 + nf * 16 + r16;
            attn[(size_t)row * 512 + col] = (_Float16)(oacc[nf][r] * inv);
        }
    }
}

// ---------------- layernorm: 1 wave per row of 512, f16 in ----------------
// OUTF32=1: write f32 (+tail); else write f16.
template <int OUTF32>
__global__ void __launch_bounds__(256) k_ln(const _Float16* __restrict__ x,
                                            const float* __restrict__ g,
                                            const float* __restrict__ b,
                                            float* __restrict__ outf,
                                            _Float16* __restrict__ outh,
                                            float* __restrict__ tail) {
    int row = blockIdx.x * 4 + (threadIdx.x >> 6);
    int lane = threadIdx.x & 63;
    h8 v = *(const h8*)(x + (size_t)row * 512 + lane * 8);
    float f[8];
    float s = 0.f, sq = 0.f;
#pragma unroll
    for (int j = 0; j < 8; ++j) {
        f[j] = (float)v[j];
        s += f[j];
        sq += f[j] * f[j];
    }
#pragma unroll
    for (int msk = 1; msk < 64; msk <<= 1) {
        s += __shfl_xor(s, msk);
        sq += __shfl_xor(sq, msk);
    }
    float mu = s * (1.f / 512.f);
    float var = sq * (1.f / 512.f) - mu * mu;
    float rstd = rsqrtf(var + 1e-5f);
    float4 ga = *(const float4*)(g + lane * 8);
    float4 gb = *(const float4*)(g + lane * 8 + 4);
    float4 ba = *(const float4*)(b + lane * 8);
    float4 bb = *(const float4*)(b + lane * 8 + 4);
    float o[8];
    o[0] = (f[0] - mu) * rstd * ga.x + ba.x;
    o[1] = (f[1] - mu) * rstd * ga.y + ba.y;
    o[2] = (f[2] - mu) * rstd * ga.z + ba.z;
    o[3] = (f[3] - mu) * rstd * ga.w + ba.w;
    o[4] = (f[4] - mu) * rstd * gb.x + bb.x;
    o[5] = (f[5] - mu) * rstd * gb.y + bb.y;
    o[6] = (f[6] - mu) * rstd * gb.z + bb.z;
    o[7] = (f[7] - mu) * rstd * gb.w + bb.w;
    if constexpr (OUTF32) {
        float* orow = outf + (size_t)row * 512 + lane * 8;
        *(float4*)(orow) = make_float4(o[0], o[1], o[2], o[3]);
        *(float4*)(orow + 4) = make_float4(o[4], o[5], o[6], o[7]);
        if (tail && blockIdx.x == 0 && threadIdx.x == 0) tail[0] = 0.f;
    } else {
        h8 oh = {(_Float16)o[0], (_Float16)o[1], (_Float16)o[2], (_Float16)o[3],
                 (_Float16)o[4], (_Float16)o[5], (_Float16)o[6], (_Float16)o[7]};
        *(h8*)(outh + (size_t)row * 512 + lane * 8) = oh;
    }
}

// ---------------- launch ----------------
extern "C" void kernel_launch(void* const* d_in, const int* in_sizes, int n_in,
                              void* d_out, int out_size, void* d_ws, size_t ws_size,
                              hipStream_t stream) {
    const float* x   = (const float*)d_in[0];
    const float* Wq  = (const float*)d_in[1];
    const float* Wk  = (const float*)d_in[2];
    const float* Wv  = (const float*)d_in[3];
    const float* Wo  = (const float*)d_in[4];
    const float* bo  = (const float*)d_in[5];
    const float* g1  = (const float*)d_in[6];
    const float* b1  = (const float*)d_in[7];
    const float* W1  = (const float*)d_in[8];
    const float* bf1 = (const float*)d_in[9];
    const float* W2  = (const float*)d_in[10];
    const float* bf2 = (const float*)d_in[11];
    const float* g2  = (const float*)d_in[12];
    const float* b2  = (const float*)d_in[13];
    float* out = (float*)d_out;

    char* ws = (char*)d_ws;
    _Float16* xh    = (_Float16*)(ws + 0);            // 8 MB; reused as out1h after QKV GEMM
    _Float16* wqkvT = (_Float16*)(ws + 8388608);      // 1.5 MB  [1536][512]
    _Float16* woT   = (_Float16*)(ws + 9961472);      // 0.5 MB
    _Float16* w1T   = (_Float16*)(ws + 10485760);     // 2 MB    [2048][512]
    _Float16* w2T   = (_Float16*)(ws + 12582912);     // 2 MB    [512][2048]
    _Float16* qb    = (_Float16*)(ws + 14680064);     // 8 MB; ff (32 MB) reuses qb..attnb
    _Float16* kb    = (_Float16*)(ws + 23068672);     // 8 MB
    _Float16* vtb   = (_Float16*)(ws + 31457280);     // 8 MB
    _Float16* attnb = (_Float16*)(ws + 39845888);     // 8 MB
    _Float16* h1h   = (_Float16*)(ws + 48234496);     // 8 MB f16 (h1, reused as h2)
    _Float16* out1h = xh;
    _Float16* ff    = qb;

    // stage 0: fused dtype conversion + weight transposes
    k_pre<<<dim3(1024, 1, 13), 256, 0, stream>>>(x, xh, Wq, Wk, Wv, Wo, W1, W2,
                                                 wqkvT, woT, w1T, w2T);

    // QKV projection (fused, N=1536): BN=128 -> grid 12*128 = 1536
    k_gemm<128, 0><<<dim3(1536), 256, 0, stream>>>(
        xh, wqkvT, M_, 1536, 512, nullptr, nullptr, nullptr, nullptr, qb, kb, vtb);

    // attention: 1024 blocks, XCD-decoded
    k_attn<<<dim3(1024), 256, 0, stream>>>(qb, kb, vtb, attnb);

    // Wo projection + bias + residual(x, f32) -> h1h (f16): BN=64 -> grid 1024
    k_gemm<64, 1><<<dim3(1024), 256, 0, stream>>>(
        attnb, woT, M_, 512, 512, bo, x, nullptr, h1h, nullptr, nullptr, nullptr);

    // LN1 -> out1h (f16)
    k_ln<0><<<dim3(M_ / 4), 256, 0, stream>>>(h1h, g1, b1, nullptr, out1h, nullptr);

    // FFN1: relu(out1 @ W1 + bf1) -> ff (f16): BN=128 -> grid 2048
    k_gemm<128, 2><<<dim3(2048), 256, 0, stream>>>(
        out1h, w1T, M_, 2048, 512, bf1, nullptr, nullptr, ff, nullptr, nullptr, nullptr);

    // FFN2: ff @ W2 + bf2 + out1 (f16 residual) -> h1h reused (f16): BN=64
    k_gemm<64, 3><<<dim3(1024), 256, 0, stream>>>(
        ff, w2T, M_, 512, 2048, bf2, nullptr, out1h, h1h, nullptr, nullptr, nullptr);

    // LN2 -> d_out (fp32) + trailing scalar (reference returns (out3, 0))
    k_ln<1><<<dim3(M_ / 4), 256, 0, stream>>>(h1h, g2, b2, out, nullptr, out + (size_t)M_ * E_);
}

// Round 10
// 139.612 us; speedup vs baseline: 2.0130x; 1.0277x over previous
//
#include <hip/hip_runtime.h>
#include <cstdint>
#include <cstddef>

// ---------------- types ----------------
typedef _Float16 h8 __attribute__((ext_vector_type(8)));
typedef _Float16 h4 __attribute__((ext_vector_type(4)));
typedef __fp16   g2 __attribute__((ext_vector_type(2)));   // cvt_pkrtz result type
typedef float    f32x4 __attribute__((ext_vector_type(4)));

constexpr int B_ = 8, N_ = 1024, E_ = 512, H_ = 8, D_ = 64, F_ = 2048;
constexpr int M_ = B_ * N_;   // 8192 rows
constexpr int HD_ = H_ * D_;  // 512

// q pre-scale: 1/sqrt(D) * log2(e)  (softmax done in base 2)
#define QSCALE2 0.18033688011112042f

#define GLOAD_LDS16(gp, lp)                                                        \
    __builtin_amdgcn_global_load_lds((const __attribute__((address_space(1))) void*)(gp), \
                                     (__attribute__((address_space(3))) void*)(lp), 16, 0, 0)

// raw hardware exp2 (no libm denormal guard; underflow -> 0 is fine for softmax)
__device__ __forceinline__ float exp2_raw(float x) {
#if __has_builtin(__builtin_amdgcn_exp2f)
    return __builtin_amdgcn_exp2f(x);
#else
    float r;
    asm("v_exp_f32 %0, %1\n\ts_nop 0" : "=v"(r) : "v"(x));
    return r;
#endif
}

// ---------------- fused prep: weight transposes (z<12) + x f32->f16 (z==12) ----
__global__ void __launch_bounds__(256) k_pre(
    const float* __restrict__ x, _Float16* __restrict__ xh,
    const float* __restrict__ Wq, const float* __restrict__ Wk,
    const float* __restrict__ Wv, const float* __restrict__ Wo,
    const float* __restrict__ W1, const float* __restrict__ W2,
    _Float16* __restrict__ oqkv, _Float16* __restrict__ oo,
    _Float16* __restrict__ o1, _Float16* __restrict__ o2) {
    if (blockIdx.z == 12) {
        // cvt: 1024 x-blocks * 256 threads * 16 elems = 4,194,304 = M_*E_
        int i = (blockIdx.x * 256 + threadIdx.x) * 16;
#pragma unroll
        for (int j = 0; j < 4; ++j) {
            float4 v = *(const float4*)(x + i + j * 4);
            h4 o = {(_Float16)v.x, (_Float16)v.y, (_Float16)v.z, (_Float16)v.w};
            *(h4*)(xh + i + j * 4) = o;
        }
        return;
    }
    if (blockIdx.x >= 256) return;
    const float* in;
    _Float16* out;
    int R, C, gt = blockIdx.x;
    switch (blockIdx.z) {
        case 0: in = Wq; out = oqkv;              R = 512;  C = 512;  break;
        case 1: in = Wk; out = oqkv + 512 * 512;  R = 512;  C = 512;  break;
        case 2: in = Wv; out = oqkv + 1024 * 512; R = 512;  C = 512;  break;
        case 3: in = Wo; out = oo;                R = 512;  C = 512;  break;
        default:
            if (blockIdx.z < 8) { in = W1; out = o1; R = 512;  C = 2048; gt += (blockIdx.z - 4) * 256; }
            else                { in = W2; out = o2; R = 2048; C = 512;  gt += (blockIdx.z - 8) * 256; }
    }
    const int ctiles = C >> 5;
    const int ty = gt / ctiles, tx = gt - ty * ctiles;
    const int r0 = ty * 32, c0 = tx * 32;
    __shared__ float lt[32][33];
    const int rr = threadIdx.x >> 3, cq = threadIdx.x & 7;
    float4 v = *(const float4*)&in[(size_t)(r0 + rr) * C + c0 + cq * 4];
    lt[rr][cq * 4 + 0] = v.x; lt[rr][cq * 4 + 1] = v.y;
    lt[rr][cq * 4 + 2] = v.z; lt[rr][cq * 4 + 3] = v.w;
    __syncthreads();
    h4 o = {(_Float16)lt[cq * 4 + 0][rr], (_Float16)lt[cq * 4 + 1][rr],
            (_Float16)lt[cq * 4 + 2][rr], (_Float16)lt[cq * 4 + 3][rr]};
    *(h4*)&out[(size_t)(c0 + rr) * R + r0 + cq * 4] = o;
}

// ---------------- GEMM: C = A[M][K] * Bt[N][K]^T, f16 in, fp32 acc ----------------
// BM=64 fixed; BN templated. XCD-aware 1-D grid decode (T1), XOR-swizzled LDS (T2),
// 2-phase double-buffered prefetch (T3-min).
// EPI 0: QKV scatter (q *= QSCALE2, k direct, v transposed via LDS)
// EPI 1: outh = f16(acc + bias[col] + res_f32[row][col])   (Wo + x residual)
// EPI 2: outh = relu(acc + bias[col])                      (f16)
// EPI 3: outh = f16(acc + bias[col] + resh_f16[row][col])  (FFN2 + out1 residual)
template <int BN, int EPI>
__global__ void __launch_bounds__(256) k_gemm(
    const _Float16* __restrict__ A, const _Float16* __restrict__ Bt,
    int Mg, int Ng, int Kg,
    const float* __restrict__ bias, const float* __restrict__ res,
    const _Float16* __restrict__ resh, _Float16* __restrict__ outh,
    _Float16* __restrict__ qp, _Float16* __restrict__ kp, _Float16* __restrict__ vtp) {
    constexpr int WN = BN / 2;       // wave tile cols
    constexpr int NI = WN / 16;      // n-frags per wave
    __shared__ alignas(16) _Float16 lA[2][64 * 64];
    __shared__ alignas(16) _Float16 lB[2][BN * 64];

    const int tid = threadIdx.x;
    const int lane = tid & 63;
    const int wid = tid >> 6;
    const int wr = wid >> 1, wc = wid & 1;
    const int r16 = lane & 15, hseg = lane >> 4;

    // XCD-aware tile decode (M tiles = 128 always: 16 per XCD)
    const int bid = blockIdx.x;
    const int xcd = bid & 7;
    const int rem = bid >> 3;
    const int tx = rem >> 4, tyl = rem & 15;
    const int m0 = (xcd * 16 + tyl) * 64;
    const int n0 = tx * BN;

    auto STAGE = [&](int buf, int k0) {
#pragma unroll
        for (int i = 0; i < 2; ++i) {
            const int slot = i * 256 + tid, row = slot >> 3;
            const int cs = (slot & 7) ^ (row & 7);
            GLOAD_LDS16(A + (size_t)(m0 + row) * Kg + k0 + cs * 8, &lA[buf][slot * 8]);
        }
#pragma unroll
        for (int i = 0; i < BN / 32; ++i) {
            const int slot = i * 256 + tid, row = slot >> 3;
            const int cs = (slot & 7) ^ (row & 7);
            GLOAD_LDS16(Bt + (size_t)(n0 + row) * Kg + k0 + cs * 8, &lB[buf][slot * 8]);
        }
    };

    f32x4 acc[2][NI] = {};
    const int nt = Kg >> 6;

    STAGE(0, 0);
    __syncthreads();  // vmcnt(0)+barrier: buf0 ready

    for (int t = 0; t < nt; ++t) {
        const int cur = t & 1;
        if (t + 1 < nt) STAGE(cur ^ 1, (t + 1) << 6);  // prefetch overlaps compute

#pragma unroll
        for (int kk = 0; kk < 2; ++kk) {
            h8 af[2], bf[NI];
#pragma unroll
            for (int mi = 0; mi < 2; ++mi) {
                const int row = wr * 32 + mi * 16 + r16;
                af[mi] = *(const h8*)&lA[cur][row * 64 + (((kk * 4 + hseg) ^ (row & 7)) * 8)];
            }
#pragma unroll
            for (int ni = 0; ni < NI; ++ni) {
                const int row = wc * WN + ni * 16 + r16;
                bf[ni] = *(const h8*)&lB[cur][row * 64 + (((kk * 4 + hseg) ^ (row & 7)) * 8)];
            }
#pragma unroll
            for (int mi = 0; mi < 2; ++mi)
#pragma unroll
                for (int ni = 0; ni < NI; ++ni)
                    acc[mi][ni] =
                        __builtin_amdgcn_mfma_f32_16x16x32_f16(af[mi], bf[ni], acc[mi][ni], 0, 0, 0);
        }
        __syncthreads();  // drains prefetch vmcnt + read lgkmcnt, guards buffer swap
    }

    // epilogue: lane holds C[row = m0+wr*32+mi*16+hseg*4+r][col = n0+wc*WN+ni*16+r16]
    if constexpr (EPI == 0) {
        if (n0 >= 1024) {
            // V block: transpose 64xBN C-tile through LDS, coalesced h8 stores.
            _Float16* lC = &lA[0][0];
#pragma unroll
            for (int mi = 0; mi < 2; ++mi) {
                const int r0 = wr * 32 + mi * 16 + hseg * 4;
                const int s = r0 >> 3, ro = r0 & 7;
#pragma unroll
                for (int ni = 0; ni < NI; ++ni) {
                    const int c = wc * WN + ni * 16 + r16;
                    h4 pv = {(_Float16)acc[mi][ni][0], (_Float16)acc[mi][ni][1],
                             (_Float16)acc[mi][ni][2], (_Float16)acc[mi][ni][3]};
                    *(h4*)&lC[c * 64 + ((s ^ (c & 7)) << 3) + ro] = pv;
                }
            }
            __syncthreads();
            const int c = tid >> 1, half = tid & 1;
            const int b = m0 >> 10, nn0 = m0 & 1023;
            _Float16* gdst =
                vtp + ((size_t)(b * 512 + (n0 - 1024) + c)) * 1024 + nn0 + half * 32;
#pragma unroll
            for (int j = 0; j < 4; ++j) {
                const int s = half * 4 + j;
                h8 v = *(const h8*)&lC[c * 64 + ((s ^ (c & 7)) << 3)];
                *(h8*)&gdst[j * 8] = v;
            }
        } else {
#pragma unroll
            for (int mi = 0; mi < 2; ++mi)
#pragma unroll
                for (int ni = 0; ni < NI; ++ni)
#pragma unroll
                    for (int r = 0; r < 4; ++r) {
                        int row = m0 + wr * 32 + mi * 16 + hseg * 4 + r;
                        int col = n0 + wc * WN + ni * 16 + r16;
                        float v = acc[mi][ni][r];
                        int cc = col & 511;
                        int h = cc >> 6, d = cc & 63;
                        int b = row >> 10, nn = row & 1023;
                        if (col < 512)
                            qp[((b * 8 + h) * 1024 + nn) * 64 + d] = (_Float16)(v * QSCALE2);
                        else
                            kp[((b * 8 + h) * 1024 + nn) * 64 + d] = (_Float16)v;
                    }
        }
    } else {
#pragma unroll
        for (int mi = 0; mi < 2; ++mi)
#pragma unroll
            for (int ni = 0; ni < NI; ++ni)
#pragma unroll
                for (int r = 0; r < 4; ++r) {
                    int row = m0 + wr * 32 + mi * 16 + hseg * 4 + r;
                    int col = n0 + wc * WN + ni * 16 + r16;
                    float v = acc[mi][ni][r] + bias[col];
                    if constexpr (EPI == 1) {
                        v += res[(size_t)row * Ng + col];
                    } else if constexpr (EPI == 3) {
                        v += (float)resh[(size_t)row * Ng + col];
                    } else {
                        v = v > 0.f ? v : 0.f;
                    }
                    outh[(size_t)row * Ng + col] = (_Float16)v;
                }
    }
}

// ---------------- flash attention: 1 block = (b,h) x 128 q-rows, 8 waves --------
// 8 waves share each K/V tile (staging traffic halved; 512 threads stage the
// 16 KB K+V pair with exactly 1+1 global_load_lds per thread). LDS ~48 KB ->
// 3 blocks/CU = 24 waves/CU for latency hiding. TILE body unchanged from R9:
// swapped QK^T, XOR-swizzle, per-lane partial softmax sum, rare defer-max rescale.
__global__ void __launch_bounds__(512) k_attn(const _Float16* __restrict__ q,
                                              const _Float16* __restrict__ k,
                                              const _Float16* __restrict__ vt,
                                              _Float16* __restrict__ attn) {
    __shared__ alignas(16) _Float16 lK[2][64 * 64];   // [key][d], swizzled
    __shared__ alignas(16) _Float16 lV[2][64 * 64];   // [d][key], swizzled
    __shared__ alignas(16) _Float16 lP[8][16 * 64];   // per-wave P tile, swizzled

    const int tid = threadIdx.x, lane = tid & 63, w = tid >> 6;
    const int bid = blockIdx.x;                  // 512 blocks = 64 per XCD
    const int xcd = bid & 7, rem = bid >> 3;
    const int bh = xcd * 8 + (rem & 7);
    const int q0 = (rem >> 3) * 128;
    const int r16 = lane & 15, hseg = lane >> 4;
    const size_t base = (size_t)bh * N_ * D_;

    // Q fragments (pre-scaled by QSCALE2 at QKV epilogue), held all kernel
    h8 qf0 = *(const h8*)&q[base + (size_t)(q0 + w * 16 + r16) * 64 + hseg * 8];
    h8 qf1 = *(const h8*)&q[base + (size_t)(q0 + w * 16 + r16) * 64 + 32 + hseg * 8];

    // per-lane swizzled staging source: slot = tid -> (row, c ^ (row&7))
    const int srow = tid >> 3;
    const int scsrc = (tid & 7) ^ (srow & 7);

    auto STAGE = [&](int buf, int kt) {
        GLOAD_LDS16(k + base + kt * 4096 + srow * 64 + scsrc * 8, &lK[buf][tid * 8]);
        GLOAD_LDS16(vt + base + (size_t)srow * N_ + kt * 64 + scsrc * 8, &lV[buf][tid * 8]);
    };

    // softmax state for q-row r16: mrun row-shared; lrun per-lane PARTIAL
    float mrun = -1e30f, lrun = 0.f;
    f32x4 oacc[4] = {};  // O[q = hseg*4+r][d = nf*16+r16]

    // hoisted per-lane LDS byte offsets (kt-invariant)
    const char* lKb = (const char*)&lK[0][0];
    const char* lVb = (const char*)&lV[0][0];
    char* lPb = (char*)&lP[0][0] + w * 2048;
    const int swz = r16 & 7;
    const int kb0 = r16 * 128 + ((hseg ^ swz) * 16);        // kc=0 (lK & lV share)
    const int kb1 = r16 * 128 + (((4 + hseg) ^ swz) * 16);  // kc=1
    const int pswz = swz * 8;
    const int prd0 = r16 * 128 + (((hseg * 8) ^ pswz) * 2);
    const int prd1 = r16 * 128 + (((32 + hseg * 8) ^ pswz) * 2);
    const int pwr0 = r16 * 128 + (((0 + hseg * 4) ^ pswz) * 2);
    const int pwr1 = r16 * 128 + (((16 + hseg * 4) ^ pswz) * 2);
    const int pwr2 = r16 * 128 + (((32 + hseg * 4) ^ pswz) * 2);
    const int pwr3 = r16 * 128 + (((48 + hseg * 4) ^ pswz) * 2);

    auto TILE = [&](const int cur, const int kt) __attribute__((always_inline)) {
        if (kt + 1 < N_ / 64) STAGE(cur ^ 1, kt + 1);  // prefetch overlaps compute
        const int cOff = cur * 8192;  // one buffer = 64*64*2 bytes

        // S tiles swapped: sv[t4][r] = S[key = t4*16 + hseg*4 + r][q = r16]
        float sv[4][4];
        __builtin_amdgcn_s_setprio(1);
#pragma unroll
        for (int t4 = 0; t4 < 4; ++t4) {
            f32x4 a = {};
            h8 kf0 = *(const h8*)(lKb + cOff + t4 * 2048 + kb0);
            a = __builtin_amdgcn_mfma_f32_16x16x32_f16(kf0, qf0, a, 0, 0, 0);
            h8 kf1 = *(const h8*)(lKb + cOff + t4 * 2048 + kb1);
            a = __builtin_amdgcn_mfma_f32_16x16x32_f16(kf1, qf1, a, 0, 0, 0);
#pragma unroll
            for (int r = 0; r < 4; ++r) sv[t4][r] = a[r];
        }
        __builtin_amdgcn_s_setprio(0);

        // in-lane max over this lane's 16 values (tree)
        float m0a = fmaxf(fmaxf(sv[0][0], sv[0][1]), fmaxf(sv[0][2], sv[0][3]));
        float m1a = fmaxf(fmaxf(sv[1][0], sv[1][1]), fmaxf(sv[1][2], sv[1][3]));
        float m2a = fmaxf(fmaxf(sv[2][0], sv[2][1]), fmaxf(sv[2][2], sv[2][3]));
        float m3a = fmaxf(fmaxf(sv[3][0], sv[3][1]), fmaxf(sv[3][2], sv[3][3]));
        float mx = fmaxf(fmaxf(m0a, m1a), fmaxf(m2a, m3a));

        // rescale only if some lane's local max breaches the threshold (rare)
        if (__any(mx > mrun + 8.f)) {
            mx = fmaxf(mx, __shfl_xor(mx, 16));
            mx = fmaxf(mx, __shfl_xor(mx, 32));
            float mnew = fmaxf(mrun, mx);
            float sc = exp2_raw(mrun - mnew);
            mrun = mnew;
            lrun *= sc;  // per-lane partial; sc row-uniform -> consistent
#pragma unroll
            for (int r = 0; r < 4; ++r) {
                float scq = __shfl(sc, hseg * 4 + r);
#pragma unroll
                for (int nf = 0; nf < 4; ++nf) oacc[nf][r] *= scq;
            }
        }

        // P = exp2(S - m); per-lane partial sum only (cross-lane deferred to end)
        float p[4][4];
        float rsum = 0.f;
#pragma unroll
        for (int t4 = 0; t4 < 4; ++t4)
#pragma unroll
            for (int r = 0; r < 4; ++r) {
                p[t4][r] = exp2_raw(sv[t4][r] - mrun);
                rsum += p[t4][r];
            }
        lrun += rsum;

        // P -> A-operand layout via per-wave LDS (packed converts, b64 writes)
#pragma unroll
        for (int t4 = 0; t4 < 4; ++t4) {
            g2 a0 = __builtin_amdgcn_cvt_pkrtz(p[t4][0], p[t4][1]);
            g2 a1 = __builtin_amdgcn_cvt_pkrtz(p[t4][2], p[t4][3]);
            h4 pv = {(_Float16)a0[0], (_Float16)a0[1], (_Float16)a1[0], (_Float16)a1[1]};
            char* dst = lPb + (t4 == 0 ? pwr0 : t4 == 1 ? pwr1 : t4 == 2 ? pwr2 : pwr3);
            *(h4*)dst = pv;
        }
        asm volatile("s_waitcnt lgkmcnt(0)" ::: "memory");  // wave-internal LDS fence

        h8 pa0 = *(const h8*)(lPb + prd0);
        h8 pa1 = *(const h8*)(lPb + prd1);
        __builtin_amdgcn_s_setprio(1);
#pragma unroll
        for (int nf = 0; nf < 4; ++nf) {
            h8 vb0 = *(const h8*)(lVb + cOff + nf * 2048 + kb0);
            oacc[nf] = __builtin_amdgcn_mfma_f32_16x16x32_f16(pa0, vb0, oacc[nf], 0, 0, 0);
            h8 vb1 = *(const h8*)(lVb + cOff + nf * 2048 + kb1);
            oacc[nf] = __builtin_amdgcn_mfma_f32_16x16x32_f16(pa1, vb1, oacc[nf], 0, 0, 0);
        }
        __builtin_amdgcn_s_setprio(0);
        __syncthreads();  // drains prefetch vmcnt + guards buffer swap
    };

    STAGE(0, 0);
    __syncthreads();  // drains vmcnt: buf0 ready

    for (int kt = 0; kt < N_ / 64; kt += 2) {
        TILE(0, kt);
        TILE(1, kt + 1);
    }

    // reduce the deferred partial sums (2 shuffles, once per kernel)
    lrun += __shfl_xor(lrun, 16);
    lrun += __shfl_xor(lrun, 32);

    // write attn_out [M][HD] f16; 1/l broadcast to C-row layout
    float rlin = 1.f / lrun;
    int b = bh >> 3, h = bh & 7;
#pragma unroll
    for (int r = 0; r < 4; ++r) {
        float inv = __shfl(rlin, hseg * 4 + r);
        int row = b * 1024 + q0 + w * 16 + hseg * 4 + r;
#pragma unroll
        for (int nf = 0; nf < 4; ++nf) {
            int col = h * 64 + nf * 16 + r16;
            attn[(size_t)row * 512 + col] = (_Float16)(oacc[nf][r] * inv);
        }
    }
}

// ---------------- layernorm: 1 wave per row of 512, f16 in ----------------
// OUTF32=1: write f32 (+tail); else write f16.
template <int OUTF32>
__global__ void __launch_bounds__(256) k_ln(const _Float16* __restrict__ x,
                                            const float* __restrict__ g,
                                            const float* __restrict__ b,
                                            float* __restrict__ outf,
                                            _Float16* __restrict__ outh,
                                            float* __restrict__ tail) {
    int row = blockIdx.x * 4 + (threadIdx.x >> 6);
    int lane = threadIdx.x & 63;
    h8 v = *(const h8*)(x + (size_t)row * 512 + lane * 8);
    float f[8];
    float s = 0.f, sq = 0.f;
#pragma unroll
    for (int j = 0; j < 8; ++j) {
        f[j] = (float)v[j];
        s += f[j];
        sq += f[j] * f[j];
    }
#pragma unroll
    for (int msk = 1; msk < 64; msk <<= 1) {
        s += __shfl_xor(s, msk);
        sq += __shfl_xor(sq, msk);
    }
    float mu = s * (1.f / 512.f);
    float var = sq * (1.f / 512.f) - mu * mu;
    float rstd = rsqrtf(var + 1e-5f);
    float4 ga = *(const float4*)(g + lane * 8);
    float4 gb = *(const float4*)(g + lane * 8 + 4);
    float4 ba = *(const float4*)(b + lane * 8);
    float4 bb = *(const float4*)(b + lane * 8 + 4);
    float o[8];
    o[0] = (f[0] - mu) * rstd * ga.x + ba.x;
    o[1] = (f[1] - mu) * rstd * ga.y + ba.y;
    o[2] = (f[2] - mu) * rstd * ga.z + ba.z;
    o[3] = (f[3] - mu) * rstd * ga.w + ba.w;
    o[4] = (f[4] - mu) * rstd * gb.x + bb.x;
    o[5] = (f[5] - mu) * rstd * gb.y + bb.y;
    o[6] = (f[6] - mu) * rstd * gb.z + bb.z;
    o[7] = (f[7] - mu) * rstd * gb.w + bb.w;
    if constexpr (OUTF32) {
        float* orow = outf + (size_t)row * 512 + lane * 8;
        *(float4*)(orow) = make_float4(o[0], o[1], o[2], o[3]);
        *(float4*)(orow + 4) = make_float4(o[4], o[5], o[6], o[7]);
        if (tail && blockIdx.x == 0 && threadIdx.x == 0) tail[0] = 0.f;
    } else {
        h8 oh = {(_Float16)o[0], (_Float16)o[1], (_Float16)o[2], (_Float16)o[3],
                 (_Float16)o[4], (_Float16)o[5], (_Float16)o[6], (_Float16)o[7]};
        *(h8*)(outh + (size_t)row * 512 + lane * 8) = oh;
    }
}

// ---------------- launch ----------------
extern "C" void kernel_launch(void* const* d_in, const int* in_sizes, int n_in,
                              void* d_out, int out_size, void* d_ws, size_t ws_size,
                              hipStream_t stream) {
    const float* x   = (const float*)d_in[0];
    const float* Wq  = (const float*)d_in[1];
    const float* Wk  = (const float*)d_in[2];
    const float* Wv  = (const float*)d_in[3];
    const float* Wo  = (const float*)d_in[4];
    const float* bo  = (const float*)d_in[5];
    const float* g1  = (const float*)d_in[6];
    const float* b1  = (const float*)d_in[7];
    const float* W1  = (const float*)d_in[8];
    const float* bf1 = (const float*)d_in[9];
    const float* W2  = (const float*)d_in[10];
    const float* bf2 = (const float*)d_in[11];
    const float* g2  = (const float*)d_in[12];
    const float* b2  = (const float*)d_in[13];
    float* out = (float*)d_out;

    char* ws = (char*)d_ws;
    _Float16* xh    = (_Float16*)(ws + 0);            // 8 MB; reused as out1h after QKV GEMM
    _Float16* wqkvT = (_Float16*)(ws + 8388608);      // 1.5 MB  [1536][512]
    _Float16* woT   = (_Float16*)(ws + 9961472);      // 0.5 MB
    _Float16* w1T   = (_Float16*)(ws + 10485760);     // 2 MB    [2048][512]
    _Float16* w2T   = (_Float16*)(ws + 12582912);     // 2 MB    [512][2048]
    _Float16* qb    = (_Float16*)(ws + 14680064);     // 8 MB; ff (32 MB) reuses qb..attnb
    _Float16* kb    = (_Float16*)(ws + 23068672);     // 8 MB
    _Float16* vtb   = (_Float16*)(ws + 31457280);     // 8 MB
    _Float16* attnb = (_Float16*)(ws + 39845888);     // 8 MB
    _Float16* h1h   = (_Float16*)(ws + 48234496);     // 8 MB f16 (h1, reused as h2)
    _Float16* out1h = xh;
    _Float16* ff    = qb;

    // stage 0: fused dtype conversion + weight transposes
    k_pre<<<dim3(1024, 1, 13), 256, 0, stream>>>(x, xh, Wq, Wk, Wv, Wo, W1, W2,
                                                 wqkvT, woT, w1T, w2T);

    // QKV projection (fused, N=1536): BN=128 -> grid 12*128 = 1536
    k_gemm<128, 0><<<dim3(1536), 256, 0, stream>>>(
        xh, wqkvT, M_, 1536, 512, nullptr, nullptr, nullptr, nullptr, qb, kb, vtb);

    // attention: 512 blocks x 8 waves, XCD-decoded
    k_attn<<<dim3(512), 512, 0, stream>>>(qb, kb, vtb, attnb);

    // Wo projection + bias + residual(x, f32) -> h1h (f16): BN=64 -> grid 1024
    k_gemm<64, 1><<<dim3(1024), 256, 0, stream>>>(
        attnb, woT, M_, 512, 512, bo, x, nullptr, h1h, nullptr, nullptr, nullptr);

    // LN1 -> out1h (f16)
    k_ln<0><<<dim3(M_ / 4), 256, 0, stream>>>(h1h, g1, b1, nullptr, out1h, nullptr);

    // FFN1: relu(out1 @ W1 + bf1) -> ff (f16): BN=128 -> grid 2048
    k_gemm<128, 2><<<dim3(2048), 256, 0, stream>>>(
        out1h, w1T, M_, 2048, 512, bf1, nullptr, nullptr, ff, nullptr, nullptr, nullptr);

    // FFN2: ff @ W2 + bf2 + out1 (f16 residual) -> h1h reused (f16): BN=64
    k_gemm<64, 3><<<dim3(1024), 256, 0, stream>>>(
        ff, w2T, M_, 512, 2048, bf2, nullptr, out1h, h1h, nullptr, nullptr, nullptr);

    // LN2 -> d_out (fp32) + trailing scalar (reference returns (out3, 0))
    k_ln<1><<<dim3(M_ / 4), 256, 0, stream>>>(h1h, g2, b2, out, nullptr, out + (size_t)M_ * E_);
}